// Round 11
// baseline (571.148 us; speedup 1.0000x reference)
//
#include <hip/hip_runtime.h>

// Convolution_1228360646680 — equivariant graph conv, all-streaming version
// N=25000, E=400000, MUL=32, NSC=8, HID=64
//
// Fast path (all hot loops barrier-free, forward-streaming):
//   prep:     scaled W1s (8x64 f32), W2T (fallback), W2Tb (128x64 bf16)
//   node_in:  xsv1[n][128] = a[n]/sqrt(32) * (x @ w1)
//   CSR sort: count -> scan -> scatter (elist/esrc/eattr/dst into dst-sorted order) + pad
//   edge_mlp_v2: MFMA per 16-edge tile (proven frag math) + LDS transpose ->
//             wbuf[k][128] bf16 ROW-MAJOR, coalesced stores, sorted order
//   xperm:    xrow[k][128] bf16 = xsv1[esrc_s[k]]  (the only scattered read, pure copy)
//   gather_seg<XROW>: block = 256 sorted edges, thread = feature; all reads are
//             affine streams (wbuf/xrow/eattr/dst); segmented flush-before-add
//             -> coalesced atomicAdd row per dst-run into mid
//   node_out: out[n][128] = b[n]/sqrt(64)/sqrt(16) * (mid @ w2)
// ws too small for xrow -> gather_seg<false> (direct xsv1); even smaller -> atomic path.

typedef __attribute__((ext_vector_type(8))) short bf16x8;
typedef __attribute__((ext_vector_type(4))) float f32x4;

__device__ __forceinline__ unsigned bf16r(float x) {
    unsigned u = __float_as_uint(x);
    return (u + 0x7fffu + ((u >> 16) & 1u)) >> 16;   // RNE
}
__device__ __forceinline__ float bf16tof(unsigned short v) {
    return __uint_as_float(((unsigned)v) << 16);
}

__global__ __launch_bounds__(256) void prep_kernel(
    const float* __restrict__ Wfc1, const float* __restrict__ Wfc2,
    float* __restrict__ W1s, float* __restrict__ W2T, unsigned short* __restrict__ W2Tb)
{
    int t = blockIdx.x * 256 + threadIdx.x;
    const float inv_sqrt_nsc = 0.35355339059327373f; // 1/sqrt(8)
    if (t < 8 * 64) W1s[t] = Wfc1[t] * inv_sqrt_nsc;
    if (t < 64 * 128) {
        int r = t >> 7, c = t & 127;
        float v = Wfc2[t] * 0.125f;                  // 1/sqrt(64)
        W2T[c * 64 + r] = v;
        W2Tb[c * 64 + r] = (unsigned short)bf16r(v);
    }
}

__global__ __launch_bounds__(256) void node_in_kernel(
    const float* __restrict__ node_input, const float* __restrict__ attr_in,
    const float* __restrict__ w1s, const float* __restrict__ w1v,
    float* __restrict__ xsv1, int n_nodes)
{
    __shared__ float sWs[1024], sWv[1024], srow[2][128];
    for (int k = threadIdx.x; k < 1024; k += 256) { sWs[k] = w1s[k]; sWv[k] = w1v[k]; }
    int j = threadIdx.x & 127;
    int half = threadIdx.x >> 7;
    int w = 0, i = 0;
    if (j >= 32) { int jj = j - 32; w = jj / 3; i = jj - 3 * w; }
    const float inv1 = 0.17677669529663687f; // 1/sqrt(32)
    for (int base = blockIdx.x * 2; base < n_nodes; base += gridDim.x * 2) {
        int n = base + half;
        __syncthreads();
        if (n < n_nodes) srow[half][j] = node_input[(size_t)n * 128 + j];
        __syncthreads();
        if (n < n_nodes) {
            float acc = 0.0f;
            if (j < 32) {
                #pragma unroll
                for (int u = 0; u < 32; u++) acc += srow[half][u] * sWs[u * 32 + j];
            } else {
                #pragma unroll
                for (int u = 0; u < 32; u++) acc += srow[half][32 + 3 * u + i] * sWv[u * 32 + w];
            }
            xsv1[(size_t)n * 128 + j] = acc * (attr_in[n] * inv1);
        }
    }
}

// ---------------- CSR build ----------------
__global__ __launch_bounds__(256) void count_kernel(
    const int* __restrict__ edst, int* __restrict__ counts, int n_edges)
{
    int e = blockIdx.x * 256 + threadIdx.x;
    if (e < n_edges) atomicAdd(&counts[edst[e]], 1);
}

__global__ __launch_bounds__(1024) void scan_kernel(
    const int* __restrict__ counts, int* __restrict__ offs, int* __restrict__ cursor, int n)
{
    __shared__ int part[1024];
    int tid = threadIdx.x;
    int chunk = (n + 1023) / 1024;
    int begin = tid * chunk;
    int end = begin + chunk; if (end > n) end = n;
    int s = 0;
    for (int i = begin; i < end; i++) s += counts[i];
    part[tid] = s;
    __syncthreads();
    for (int off = 1; off < 1024; off <<= 1) {
        int v = (tid >= off) ? part[tid - off] : 0;
        __syncthreads();
        part[tid] += v;
        __syncthreads();
    }
    int base = (tid == 0) ? 0 : part[tid - 1];
    for (int i = begin; i < end; i++) {
        offs[i] = base; cursor[i] = base;
        base += counts[i];
    }
    if (tid == 1023) offs[n] = part[1023];
}

__global__ __launch_bounds__(256) void scatter_kernel(
    const int* __restrict__ edst, const int* __restrict__ esrc,
    const float* __restrict__ eattr,
    int* __restrict__ cursor, int* __restrict__ elist,
    int* __restrict__ esrc_s, float4* __restrict__ eattr_s, int* __restrict__ dst_s,
    int n_edges)
{
    int e = blockIdx.x * 256 + threadIdx.x;
    if (e < n_edges) {
        int d = edst[e];
        int p = atomicAdd(&cursor[d], 1);
        elist[p] = e;
        esrc_s[p] = esrc[e];
        dst_s[p] = d;
        eattr_s[p] = *reinterpret_cast<const float4*>(eattr + (size_t)e * 4);
    }
}

__global__ __launch_bounds__(256) void pad_init_kernel(
    int* __restrict__ esrc_s, float4* __restrict__ eattr_s, int* __restrict__ dst_s,
    int n_edges, int n_pad, int n_nodes)
{
    int k = n_edges + threadIdx.x;
    if (k < n_pad) {
        esrc_s[k] = 0;
        dst_s[k] = n_nodes;                 // scratch row
        eattr_s[k] = make_float4(0.f, 0.f, 0.f, 0.f);
    }
    if (threadIdx.x == 0) dst_s[n_pad] = -1;
}

// ---------------- edge MLP via MFMA -> row-major bf16 wbuf (coalesced) ----------------
__global__ __launch_bounds__(256) void edge_mlp_v2(
    const float* __restrict__ escal, const int* __restrict__ elist,
    const float* __restrict__ W1s, const unsigned short* __restrict__ W2Tb,
    unsigned short* __restrict__ wbuf, int n_edges)
{
    __shared__ unsigned short w_lds[4][2048];   // 4 waves x 16x128 bf16 (tile-frag layout)

    int tid = threadIdx.x;
    int wv = tid >> 6, l = tid & 63;
    int lm = l & 15, lk = l >> 4;
    int kbase = blockIdx.x * 64;
    int rt = blockIdx.x * 4 + wv;
    int kidx = rt * 16 + lm;
    int k0 = lk * 8;

    // B fragments: 8 col-tiles x 2 K-halves (validated)
    bf16x8 bf[8][2];
    #pragma unroll
    for (int t = 0; t < 8; t++) {
        int n = t * 16 + lm;
        bf[t][0] = *reinterpret_cast<const bf16x8*>(W2Tb + n * 64 + k0);
        bf[t][1] = *reinterpret_cast<const bf16x8*>(W2Tb + n * 64 + k0 + 32);
    }

    float q[8];
    if (kidx < n_edges) {
        int e = elist[kidx];
        float4 qa = *reinterpret_cast<const float4*>(escal + (size_t)e * 8);
        float4 qb = *reinterpret_cast<const float4*>(escal + (size_t)e * 8 + 4);
        q[0] = qa.x; q[1] = qa.y; q[2] = qa.z; q[3] = qa.w;
        q[4] = qb.x; q[5] = qb.y; q[6] = qb.z; q[7] = qb.w;
    } else {
        #pragma unroll
        for (int i = 0; i < 8; i++) q[i] = 0.f;
    }

    // h = silu(q @ W1s) -> two A fragments (validated layout)
    union Af { bf16x8 v; unsigned u[4]; };
    Af af0, af1;
    #pragma unroll
    for (int half = 0; half < 2; half++) {
        int kb = k0 + half * 32;
        float h[8];
        #pragma unroll
        for (int i = 0; i < 8; i++) h[i] = 0.f;
        #pragma unroll
        for (int in = 0; in < 8; in++) {
            float qi = q[in];
            float4 wa = *reinterpret_cast<const float4*>(W1s + in * 64 + kb);
            float4 wb = *reinterpret_cast<const float4*>(W1s + in * 64 + kb + 4);
            h[0] += qi * wa.x; h[1] += qi * wa.y; h[2] += qi * wa.z; h[3] += qi * wa.w;
            h[4] += qi * wb.x; h[5] += qi * wb.y; h[6] += qi * wb.z; h[7] += qi * wb.w;
        }
        unsigned* dst = half ? af1.u : af0.u;
        #pragma unroll
        for (int p = 0; p < 4; p++) {
            float s0 = h[2 * p], s1 = h[2 * p + 1];
            s0 = s0 / (1.0f + __expf(-s0));
            s1 = s1 / (1.0f + __expf(-s1));
            dst[p] = bf16r(s0) | (bf16r(s1) << 16);
        }
    }

    // MFMA -> C-frags -> w_lds in tile-frag layout
    #pragma unroll
    for (int t = 0; t < 8; t++) {
        f32x4 a4 = {0.f, 0.f, 0.f, 0.f};
        a4 = __builtin_amdgcn_mfma_f32_16x16x32_bf16(af0.v, bf[t][0], a4, 0, 0, 0);
        a4 = __builtin_amdgcn_mfma_f32_16x16x32_bf16(af1.v, bf[t][1], a4, 0, 0, 0);
        unsigned s0 = bf16r(a4[0]) | (bf16r(a4[1]) << 16);
        unsigned s1 = bf16r(a4[2]) | (bf16r(a4[3]) << 16);
        *reinterpret_cast<uint2*>(&w_lds[wv][t * 256 + l * 4]) = make_uint2(s0, s1);
    }
    __syncthreads();

    // transpose-out: coalesced row-major stores, 4 x uint4 per thread
    #pragma unroll
    for (int s = 0; s < 4; s++) {
        int flat = s * 256 + tid;            // 1024 chunks of 16B
        int m = flat >> 4;                   // local edge 0..63
        int part = flat & 15;                // 8-col group
        int wv2 = m >> 4, m2 = m & 15;
        union { unsigned short us[8]; uint4 v; } pk;
        #pragma unroll
        for (int z = 0; z < 8; z++) {
            int c = part * 8 + z;
            int ct = c >> 4, nn = c & 15;
            pk.us[z] = w_lds[wv2][ct * 256 + ((m2 >> 2) << 6) + (nn << 2) + (m2 & 3)];
        }
        *reinterpret_cast<uint4*>(wbuf + (size_t)(kbase + m) * 128 + part * 8) = pk.v;
    }
}

// ---------------- xperm: xrow[k] = bf16(xsv1[esrc_s[k]]), streaming write ----------------
__global__ __launch_bounds__(256) void xperm_kernel(
    const float* __restrict__ xsv1, const int* __restrict__ esrc_s,
    unsigned short* __restrict__ xrow, int n_pad)
{
    int total = n_pad * 16;                       // 8-bf16 chunks
    for (int idx = blockIdx.x * 256 + threadIdx.x; idx < total; idx += gridDim.x * 256) {
        int k = idx >> 4, part = idx & 15;
        int src = esrc_s[k];
        const float4* s = reinterpret_cast<const float4*>(xsv1 + (size_t)src * 128 + part * 8);
        float4 a = s[0], b = s[1];
        uint4 pk;
        pk.x = bf16r(a.x) | (bf16r(a.y) << 16);
        pk.y = bf16r(a.z) | (bf16r(a.w) << 16);
        pk.z = bf16r(b.x) | (bf16r(b.y) << 16);
        pk.w = bf16r(b.z) | (bf16r(b.w) << 16);
        *reinterpret_cast<uint4*>(xrow + (size_t)k * 128 + part * 8) = pk;
    }
}

// ---------------- gather: barrier-free, all-streaming, segmented flush ----------------
template<bool XROW>
__global__ __launch_bounds__(256) void gather_seg_kernel(
    const unsigned short* __restrict__ wbuf, const unsigned short* __restrict__ xrow,
    const float* __restrict__ xsv1, const int* __restrict__ esrc_s,
    const float4* __restrict__ eattr_s, const int* __restrict__ dst_s,
    float* __restrict__ mid)
{
    int tid = threadIdx.x;
    int kind, u = 0, i = 0, col;
    if (tid < 32)       { kind = 0; u = tid;       col = tid; }
    else if (tid < 64)  { kind = 1; u = tid - 32;  col = 96 + u; }
    else if (tid < 160) { int q = tid - 64;  u = q / 3; i = q - 3 * u; kind = 2; col = 32 + u; }
    else                { int q = tid - 160; u = q / 3; i = q - 3 * u; kind = 3; col = 64 + u; }
    const float inv_sqrt3 = 0.5773502691896258f;

    int e0 = blockIdx.x * 256;
    float acc = 0.0f;
    int dcur = dst_s[e0];

    #pragma unroll 2
    for (int c4 = 0; c4 < 64; c4++) {
        int k = e0 + c4 * 4;
        int4 d4 = *reinterpret_cast<const int4*>(dst_s + k);
        #pragma unroll
        for (int j = 0; j < 4; j++) {
            int kk = k + j;
            int d = (j == 0) ? d4.x : (j == 1) ? d4.y : (j == 2) ? d4.z : d4.w;
            if (d != dcur) {                       // uniform branch
                atomicAdd(mid + (size_t)dcur * 256 + tid, acc);
                acc = 0.0f; dcur = d;
            }
            float4 ea = eattr_s[kk];
            float wvv = bf16tof(wbuf[(size_t)kk * 128 + col]);
            float contrib;
            if (XROW) {
                const unsigned short* nb = xrow + (size_t)kk * 128;
                if (kind == 0)      contrib = wvv * bf16tof(nb[u]) * ea.x;
                else if (kind == 1) contrib = wvv * (bf16tof(nb[32 + 3 * u]) * ea.y
                                                     + bf16tof(nb[33 + 3 * u]) * ea.z
                                                     + bf16tof(nb[34 + 3 * u]) * ea.w) * inv_sqrt3;
                else if (kind == 2) { float yvi = (i == 0) ? ea.y : (i == 1) ? ea.z : ea.w;
                                      contrib = wvv * bf16tof(nb[u]) * yvi; }
                else                contrib = wvv * ea.x * bf16tof(nb[32 + 3 * u + i]);
            } else {
                int src = esrc_s[kk];
                const float* __restrict__ nb = xsv1 + (size_t)src * 128;
                if (kind == 0)      contrib = wvv * nb[u] * ea.x;
                else if (kind == 1) contrib = wvv * (nb[32 + 3 * u] * ea.y + nb[33 + 3 * u] * ea.z
                                                     + nb[34 + 3 * u] * ea.w) * inv_sqrt3;
                else if (kind == 2) { float yvi = (i == 0) ? ea.y : (i == 1) ? ea.z : ea.w;
                                      contrib = wvv * nb[u] * yvi; }
                else                contrib = wvv * ea.x * nb[32 + 3 * u + i];
            }
            acc += contrib;
        }
    }
    atomicAdd(mid + (size_t)dcur * 256 + tid, acc);  // dcur always valid (pads -> scratch)
}

// ---------------- fallback atomic edge kernel (ws too small) ----------------
__global__ __launch_bounds__(256) void edge_kernel_atomic(
    const float* __restrict__ xsv1, const int* __restrict__ esrc, const int* __restrict__ edst,
    const float* __restrict__ eattr, const float* __restrict__ escal,
    const float* __restrict__ W1s, const float* __restrict__ W2T,
    float* __restrict__ mid, int n_edges)
{
    int e = blockIdx.x * 256 + threadIdx.x;
    if (e >= n_edges) return;
    const float4 qa = *reinterpret_cast<const float4*>(escal + (size_t)e * 8);
    const float4 qb = *reinterpret_cast<const float4*>(escal + (size_t)e * 8 + 4);
    float h[64];
    #pragma unroll
    for (int t = 0; t < 64; t++) {
        float acc = qa.x * W1s[t]       + qa.y * W1s[64 + t]
                  + qa.z * W1s[128 + t] + qa.w * W1s[192 + t]
                  + qb.x * W1s[256 + t] + qb.y * W1s[320 + t]
                  + qb.z * W1s[384 + t] + qb.w * W1s[448 + t];
        h[t] = acc / (1.0f + __expf(-acc));
    }
    int src = esrc[e], dst = edst[e];
    const float4 ea = *reinterpret_cast<const float4*>(eattr + (size_t)e * 4);
    const float ys = ea.x, yv0 = ea.y, yv1 = ea.z, yv2 = ea.w;
    const float* __restrict__ nb = xsv1 + (size_t)src * 128;
    float* __restrict__ op = mid + (size_t)dst * 256;
    const float inv_sqrt3 = 0.5773502691896258f;
    for (int u = 0; u < 32; u++) {
        float w0 = 0.f, w1 = 0.f, w2 = 0.f, w3 = 0.f;
        const float* __restrict__ r0 = W2T + (size_t)u * 64;
        const float* __restrict__ r1 = W2T + (size_t)(32 + u) * 64;
        const float* __restrict__ r2 = W2T + (size_t)(64 + u) * 64;
        const float* __restrict__ r3 = W2T + (size_t)(96 + u) * 64;
        #pragma unroll
        for (int t = 0; t < 64; t++) {
            float hv = h[t];
            w0 += hv * r0[t]; w1 += hv * r1[t]; w2 += hv * r2[t]; w3 += hv * r3[t];
        }
        float es  = nb[u];
        float ev0 = nb[32 + 3 * u], ev1 = nb[33 + 3 * u], ev2 = nb[34 + 3 * u];
        atomicAdd(op + u,      w0 * es * ys);
        atomicAdd(op + 32 + u, w3 * (ev0 * yv0 + ev1 * yv1 + ev2 * yv2) * inv_sqrt3);
        float a1 = w1 * es;
        atomicAdd(op + 64 + 3 * u, a1 * yv0);
        atomicAdd(op + 65 + 3 * u, a1 * yv1);
        atomicAdd(op + 66 + 3 * u, a1 * yv2);
        float a2 = w2 * ys;
        atomicAdd(op + 160 + 3 * u, a2 * ev0);
        atomicAdd(op + 161 + 3 * u, a2 * ev1);
        atomicAdd(op + 162 + 3 * u, a2 * ev2);
    }
}

__global__ __launch_bounds__(256) void node_out_kernel(
    const float* __restrict__ mid, const float* __restrict__ attr_out,
    const float* __restrict__ w2s, const float* __restrict__ w2v,
    float* __restrict__ out, int n_nodes)
{
    __shared__ float sS0[1024], sS1[1024], sV0[1024], sV1[1024];
    for (int k = threadIdx.x; k < 1024; k += 256) {
        sS0[k] = w2s[k]; sS1[k] = w2s[1024 + k];
        sV0[k] = w2v[k]; sV1[k] = w2v[1024 + k];
    }
    __syncthreads();
    int j = threadIdx.x & 127;
    int half = threadIdx.x >> 7;
    int w = 0, i = 0;
    if (j >= 32) { int jj = j - 32; w = jj / 3; i = jj - 3 * w; }
    const float scale = 0.125f * 0.25f; // 1/sqrt(64) * 1/sqrt(16)
    for (int base = blockIdx.x * 2; base < n_nodes; base += gridDim.x * 2) {
        int n = base + half;
        if (n >= n_nodes) continue;
        const float* __restrict__ mr = mid + (size_t)n * 256;
        float acc = 0.0f;
        if (j < 32) {
            #pragma unroll
            for (int u = 0; u < 32; u++)
                acc += mr[u] * sS0[u * 32 + j] + mr[32 + u] * sS1[u * 32 + j];
        } else {
            #pragma unroll
            for (int u = 0; u < 32; u++)
                acc += mr[64 + 3 * u + i] * sV0[u * 32 + w] + mr[160 + 3 * u + i] * sV1[u * 32 + w];
        }
        out[(size_t)n * 128 + j] = acc * (attr_out[n] * scale);
    }
}

extern "C" void kernel_launch(void* const* d_in, const int* in_sizes, int n_in,
                              void* d_out, int out_size, void* d_ws, size_t ws_size,
                              hipStream_t stream)
{
    const float* node_input = (const float*)d_in[0];
    const float* attr_in    = (const float*)d_in[1];
    const float* attr_out   = (const float*)d_in[2];
    const int*   esrc       = (const int*)d_in[3];
    const int*   edst       = (const int*)d_in[4];
    const float* eattr      = (const float*)d_in[5];
    const float* escal      = (const float*)d_in[6];
    const float* w1s        = (const float*)d_in[7];
    const float* w1v        = (const float*)d_in[8];
    const float* Wfc1       = (const float*)d_in[9];
    const float* Wfc2       = (const float*)d_in[10];
    const float* w2s        = (const float*)d_in[11];
    const float* w2v        = (const float*)d_in[12];
    float* out = (float*)d_out;

    int n_nodes = in_sizes[0] / 128;
    int n_edges = in_sizes[3];
    int n_pad = ((n_edges + 255) / 256) * 256;
    int nblk = n_pad / 256;

    // workspace layout (aligned); xrow last so base plan fits proven footprint
    char* p = (char*)d_ws;
    auto alloc = [&](size_t bytes, size_t align) -> void* {
        size_t a = (size_t)p; a = (a + align - 1) & ~(align - 1);
        p = (char*)a; void* r = (void*)p; p += bytes; return r;
    };
    float* xsv1 = (float*)alloc((size_t)n_nodes * 128 * 4, 16);
    float* W1s  = (float*)alloc(512 * 4, 16);
    float* W2T  = (float*)alloc(8192 * 4, 16);
    float* mid  = (float*)alloc((size_t)(n_nodes + 1) * 256 * 4, 16);
    int* counts = (int*)alloc((size_t)n_nodes * 4, 16);
    int* offs   = (int*)alloc(((size_t)n_nodes + 1) * 4, 16);
    int* cursor = (int*)alloc((size_t)n_nodes * 4, 16);
    int* elist  = (int*)alloc((size_t)n_pad * 4, 16);
    int* esrc_s = (int*)alloc((size_t)n_pad * 4, 16);
    int* dst_s  = (int*)alloc(((size_t)n_pad + 4) * 4, 16);
    float4* eattr_s = (float4*)alloc((size_t)n_pad * 16, 16);
    unsigned short* W2Tb = (unsigned short*)alloc(8192 * 2, 64);
    unsigned short* wbuf = (unsigned short*)alloc((size_t)n_pad * 128 * 2, 64);
    size_t needed_base = (size_t)(p - (char*)d_ws);
    unsigned short* xrow = (unsigned short*)alloc((size_t)n_pad * 128 * 2, 64);
    size_t needed_full = (size_t)(p - (char*)d_ws);

    prep_kernel<<<32, 256, 0, stream>>>(Wfc1, Wfc2, W1s, W2T, W2Tb);
    node_in_kernel<<<2048, 256, 0, stream>>>(node_input, attr_in, w1s, w1v, xsv1, n_nodes);

    if (ws_size >= needed_base) {
        hipMemsetAsync(counts, 0, (size_t)n_nodes * sizeof(int), stream);
        hipMemsetAsync(mid, 0, (size_t)(n_nodes + 1) * 256 * sizeof(float), stream);
        count_kernel<<<(n_edges + 255) / 256, 256, 0, stream>>>(edst, counts, n_edges);
        scan_kernel<<<1, 1024, 0, stream>>>(counts, offs, cursor, n_nodes);
        scatter_kernel<<<(n_edges + 255) / 256, 256, 0, stream>>>(
            edst, esrc, eattr, cursor, elist, esrc_s, eattr_s, dst_s, n_edges);
        pad_init_kernel<<<1, 256, 0, stream>>>(esrc_s, eattr_s, dst_s, n_edges, n_pad, n_nodes);
        edge_mlp_v2<<<n_pad / 64, 256, 0, stream>>>(escal, elist, W1s, W2Tb, wbuf, n_edges);
        if (ws_size >= needed_full) {
            xperm_kernel<<<2048, 256, 0, stream>>>(xsv1, esrc_s, xrow, n_pad);
            gather_seg_kernel<true><<<nblk, 256, 0, stream>>>(
                wbuf, xrow, xsv1, esrc_s, eattr_s, dst_s, mid);
        } else {
            gather_seg_kernel<false><<<nblk, 256, 0, stream>>>(
                wbuf, xrow, xsv1, esrc_s, eattr_s, dst_s, mid);
        }
        node_out_kernel<<<2048, 256, 0, stream>>>(mid, attr_out, w2s, w2v, out, n_nodes);
    } else {
        hipMemsetAsync(mid, 0, (size_t)(n_nodes + 1) * 256 * sizeof(float), stream);
        edge_kernel_atomic<<<(n_edges + 255) / 256, 256, 0, stream>>>(
            xsv1, esrc, edst, eattr, escal, W1s, W2T, mid, n_edges);
        node_out_kernel<<<2048, 256, 0, stream>>>(mid, attr_out, w2s, w2v, out, n_nodes);
    }
}

// Round 12
// 499.543 us; speedup vs baseline: 1.1433x; 1.1433x over previous
//
#include <hip/hip_runtime.h>

// Convolution_1228360646680 — equivariant graph conv, wave-per-edge gather
// N=25000, E=400000, MUL=32, NSC=8, HID=64
//
// Fast path:
//   prep / node_in / CSR sort / pad: as validated (rounds 6-11)
//   edge_mlp_v2: MFMA per 16-edge tile + LDS transpose -> wbuf[k][128] bf16 row-major
//   xperm:    xrow[k][128] bf16 = xsv1[esrc_s[k]]  (only scattered read, pure copy)
//   gather_wave: each WAVE owns 64 sorted edges; lane L covers w-cols {2L,2L+1};
//             per edge: 1 coalesced w uint + 1-3 contiguous x uints + scalar eattr/dst;
//             2-6 register accumulators/lane; flush on uniform dst change via
//             contiguous atomicAdd at fbase(L)
//   node_out: out[n][128] = b[n]/sqrt(64)/sqrt(16) * (mid @ w2)
// Fallbacks as before.

typedef __attribute__((ext_vector_type(8))) short bf16x8;
typedef __attribute__((ext_vector_type(4))) float f32x4;

__device__ __forceinline__ unsigned bf16r(float x) {
    unsigned u = __float_as_uint(x);
    return (u + 0x7fffu + ((u >> 16) & 1u)) >> 16;   // RNE
}
__device__ __forceinline__ float bflo(unsigned p) { return __uint_as_float(p << 16); }
__device__ __forceinline__ float bfhi(unsigned p) { return __uint_as_float(p & 0xffff0000u); }

__global__ __launch_bounds__(256) void prep_kernel(
    const float* __restrict__ Wfc1, const float* __restrict__ Wfc2,
    float* __restrict__ W1s, float* __restrict__ W2T, unsigned short* __restrict__ W2Tb)
{
    int t = blockIdx.x * 256 + threadIdx.x;
    const float inv_sqrt_nsc = 0.35355339059327373f; // 1/sqrt(8)
    if (t < 8 * 64) W1s[t] = Wfc1[t] * inv_sqrt_nsc;
    if (t < 64 * 128) {
        int r = t >> 7, c = t & 127;
        float v = Wfc2[t] * 0.125f;                  // 1/sqrt(64)
        W2T[c * 64 + r] = v;
        W2Tb[c * 64 + r] = (unsigned short)bf16r(v);
    }
}

__global__ __launch_bounds__(256) void node_in_kernel(
    const float* __restrict__ node_input, const float* __restrict__ attr_in,
    const float* __restrict__ w1s, const float* __restrict__ w1v,
    float* __restrict__ xsv1, int n_nodes)
{
    __shared__ float sWs[1024], sWv[1024], srow[2][128];
    for (int k = threadIdx.x; k < 1024; k += 256) { sWs[k] = w1s[k]; sWv[k] = w1v[k]; }
    int j = threadIdx.x & 127;
    int half = threadIdx.x >> 7;
    int w = 0, i = 0;
    if (j >= 32) { int jj = j - 32; w = jj / 3; i = jj - 3 * w; }
    const float inv1 = 0.17677669529663687f; // 1/sqrt(32)
    for (int base = blockIdx.x * 2; base < n_nodes; base += gridDim.x * 2) {
        int n = base + half;
        __syncthreads();
        if (n < n_nodes) srow[half][j] = node_input[(size_t)n * 128 + j];
        __syncthreads();
        if (n < n_nodes) {
            float acc = 0.0f;
            if (j < 32) {
                #pragma unroll
                for (int u = 0; u < 32; u++) acc += srow[half][u] * sWs[u * 32 + j];
            } else {
                #pragma unroll
                for (int u = 0; u < 32; u++) acc += srow[half][32 + 3 * u + i] * sWv[u * 32 + w];
            }
            xsv1[(size_t)n * 128 + j] = acc * (attr_in[n] * inv1);
        }
    }
}

// ---------------- CSR build ----------------
__global__ __launch_bounds__(256) void count_kernel(
    const int* __restrict__ edst, int* __restrict__ counts, int n_edges)
{
    int e = blockIdx.x * 256 + threadIdx.x;
    if (e < n_edges) atomicAdd(&counts[edst[e]], 1);
}

__global__ __launch_bounds__(1024) void scan_kernel(
    const int* __restrict__ counts, int* __restrict__ offs, int* __restrict__ cursor, int n)
{
    __shared__ int part[1024];
    int tid = threadIdx.x;
    int chunk = (n + 1023) / 1024;
    int begin = tid * chunk;
    int end = begin + chunk; if (end > n) end = n;
    int s = 0;
    for (int i = begin; i < end; i++) s += counts[i];
    part[tid] = s;
    __syncthreads();
    for (int off = 1; off < 1024; off <<= 1) {
        int v = (tid >= off) ? part[tid - off] : 0;
        __syncthreads();
        part[tid] += v;
        __syncthreads();
    }
    int base = (tid == 0) ? 0 : part[tid - 1];
    for (int i = begin; i < end; i++) {
        offs[i] = base; cursor[i] = base;
        base += counts[i];
    }
    if (tid == 1023) offs[n] = part[1023];
}

__global__ __launch_bounds__(256) void scatter_kernel(
    const int* __restrict__ edst, const int* __restrict__ esrc,
    const float* __restrict__ eattr,
    int* __restrict__ cursor, int* __restrict__ elist,
    int* __restrict__ esrc_s, float4* __restrict__ eattr_s, int* __restrict__ dst_s,
    int n_edges)
{
    int e = blockIdx.x * 256 + threadIdx.x;
    if (e < n_edges) {
        int d = edst[e];
        int p = atomicAdd(&cursor[d], 1);
        elist[p] = e;
        esrc_s[p] = esrc[e];
        dst_s[p] = d;
        eattr_s[p] = *reinterpret_cast<const float4*>(eattr + (size_t)e * 4);
    }
}

__global__ __launch_bounds__(256) void pad_init_kernel(
    int* __restrict__ esrc_s, float4* __restrict__ eattr_s, int* __restrict__ dst_s,
    int n_edges, int n_pad, int n_nodes)
{
    int k = n_edges + threadIdx.x;
    if (k < n_pad) {
        esrc_s[k] = 0;
        dst_s[k] = n_nodes;                 // scratch row
        eattr_s[k] = make_float4(0.f, 0.f, 0.f, 0.f);
    }
    if (threadIdx.x == 0) dst_s[n_pad] = -1;
}

// ---------------- edge MLP via MFMA -> row-major bf16 wbuf (coalesced) ----------------
__global__ __launch_bounds__(256) void edge_mlp_v2(
    const float* __restrict__ escal, const int* __restrict__ elist,
    const float* __restrict__ W1s, const unsigned short* __restrict__ W2Tb,
    unsigned short* __restrict__ wbuf, int n_edges)
{
    __shared__ unsigned short w_lds[4][2048];   // 4 waves x 16x128 bf16 (tile-frag layout)

    int tid = threadIdx.x;
    int wv = tid >> 6, l = tid & 63;
    int lm = l & 15, lk = l >> 4;
    int kbase = blockIdx.x * 64;
    int rt = blockIdx.x * 4 + wv;
    int kidx = rt * 16 + lm;
    int k0 = lk * 8;

    bf16x8 bf[8][2];
    #pragma unroll
    for (int t = 0; t < 8; t++) {
        int n = t * 16 + lm;
        bf[t][0] = *reinterpret_cast<const bf16x8*>(W2Tb + n * 64 + k0);
        bf[t][1] = *reinterpret_cast<const bf16x8*>(W2Tb + n * 64 + k0 + 32);
    }

    float q[8];
    if (kidx < n_edges) {
        int e = elist[kidx];
        float4 qa = *reinterpret_cast<const float4*>(escal + (size_t)e * 8);
        float4 qb = *reinterpret_cast<const float4*>(escal + (size_t)e * 8 + 4);
        q[0] = qa.x; q[1] = qa.y; q[2] = qa.z; q[3] = qa.w;
        q[4] = qb.x; q[5] = qb.y; q[6] = qb.z; q[7] = qb.w;
    } else {
        #pragma unroll
        for (int i = 0; i < 8; i++) q[i] = 0.f;
    }

    union Af { bf16x8 v; unsigned u[4]; };
    Af af0, af1;
    #pragma unroll
    for (int half = 0; half < 2; half++) {
        int kb = k0 + half * 32;
        float h[8];
        #pragma unroll
        for (int i = 0; i < 8; i++) h[i] = 0.f;
        #pragma unroll
        for (int in = 0; in < 8; in++) {
            float qi = q[in];
            float4 wa = *reinterpret_cast<const float4*>(W1s + in * 64 + kb);
            float4 wb = *reinterpret_cast<const float4*>(W1s + in * 64 + kb + 4);
            h[0] += qi * wa.x; h[1] += qi * wa.y; h[2] += qi * wa.z; h[3] += qi * wa.w;
            h[4] += qi * wb.x; h[5] += qi * wb.y; h[6] += qi * wb.z; h[7] += qi * wb.w;
        }
        unsigned* dst = half ? af1.u : af0.u;
        #pragma unroll
        for (int p = 0; p < 4; p++) {
            float s0 = h[2 * p], s1 = h[2 * p + 1];
            s0 = s0 / (1.0f + __expf(-s0));
            s1 = s1 / (1.0f + __expf(-s1));
            dst[p] = bf16r(s0) | (bf16r(s1) << 16);
        }
    }

    #pragma unroll
    for (int t = 0; t < 8; t++) {
        f32x4 a4 = {0.f, 0.f, 0.f, 0.f};
        a4 = __builtin_amdgcn_mfma_f32_16x16x32_bf16(af0.v, bf[t][0], a4, 0, 0, 0);
        a4 = __builtin_amdgcn_mfma_f32_16x16x32_bf16(af1.v, bf[t][1], a4, 0, 0, 0);
        unsigned s0 = bf16r(a4[0]) | (bf16r(a4[1]) << 16);
        unsigned s1 = bf16r(a4[2]) | (bf16r(a4[3]) << 16);
        *reinterpret_cast<uint2*>(&w_lds[wv][t * 256 + l * 4]) = make_uint2(s0, s1);
    }
    __syncthreads();

    #pragma unroll
    for (int s = 0; s < 4; s++) {
        int flat = s * 256 + tid;
        int m = flat >> 4;
        int part = flat & 15;
        int wv2 = m >> 4, m2 = m & 15;
        union { unsigned short us[8]; uint4 v; } pk;
        #pragma unroll
        for (int z = 0; z < 8; z++) {
            int c = part * 8 + z;
            int ct = c >> 4, nn = c & 15;
            pk.us[z] = w_lds[wv2][ct * 256 + ((m2 >> 2) << 6) + (nn << 2) + (m2 & 3)];
        }
        *reinterpret_cast<uint4*>(wbuf + (size_t)(kbase + m) * 128 + part * 8) = pk.v;
    }
}

// ---------------- xperm: xrow[k] = bf16(xsv1[esrc_s[k]]) ----------------
__global__ __launch_bounds__(256) void xperm_kernel(
    const float* __restrict__ xsv1, const int* __restrict__ esrc_s,
    unsigned short* __restrict__ xrow, int n_pad)
{
    int total = n_pad * 16;
    for (int idx = blockIdx.x * 256 + threadIdx.x; idx < total; idx += gridDim.x * 256) {
        int k = idx >> 4, part = idx & 15;
        int src = esrc_s[k];
        const float4* s = reinterpret_cast<const float4*>(xsv1 + (size_t)src * 128 + part * 8);
        float4 a = s[0], b = s[1];
        uint4 pk;
        pk.x = bf16r(a.x) | (bf16r(a.y) << 16);
        pk.y = bf16r(a.z) | (bf16r(a.w) << 16);
        pk.z = bf16r(b.x) | (bf16r(b.y) << 16);
        pk.w = bf16r(b.z) | (bf16r(b.w) << 16);
        *reinterpret_cast<uint4*>(xrow + (size_t)k * 128 + part * 8) = pk;
    }
}

// ---------------- gather: wave-per-64-edges, lane = 2 w-cols, 2-6 features ----------------
__global__ __launch_bounds__(256) void gather_wave_kernel(
    const unsigned short* __restrict__ wbuf, const unsigned short* __restrict__ xrow,
    const float4* __restrict__ eattr_s, const int* __restrict__ dst_s,
    float* __restrict__ mid)
{
    int tid = threadIdx.x;
    int wv = tid >> 6, L = tid & 63;
    int w0 = blockIdx.x * 256 + wv * 64;
    int g = L >> 4;

    // lane decode: x base element, flush feature base, 6-acc flag
    int be, fbase; bool six;
    if (g == 0)      { be = 2 * L;       fbase = 2 * L;      six = false; }
    else if (g == 1) { be = 2 * L - 32;  fbase = 6 * L - 32; six = true;  }
    else if (g == 2) { be = 6 * L - 160; fbase = 6 * L - 32; six = true;  }
    else             { be = 6 * L - 256; fbase = 2 * L - 64; six = false; }

    const float inv_sqrt3 = 0.5773502691896258f;
    float a0 = 0.f, a1 = 0.f, a2 = 0.f, a3 = 0.f, a4 = 0.f, a5 = 0.f;
    int dcur = dst_s[w0];

    #pragma unroll 8
    for (int k = w0; k < w0 + 64; k++) {
        int d = dst_s[k];
        if (d != dcur) {                                // uniform scalar branch
            float* row = mid + (size_t)dcur * 256 + fbase;
            atomicAdd(row + 0, a0); atomicAdd(row + 1, a1);
            if (six) {
                atomicAdd(row + 2, a2); atomicAdd(row + 3, a3);
                atomicAdd(row + 4, a4); atomicAdd(row + 5, a5);
            }
            a0 = a1 = a2 = a3 = a4 = a5 = 0.f;
            dcur = d;
        }
        float4 ea = eattr_s[k];
        unsigned wp = *reinterpret_cast<const unsigned*>(wbuf + (size_t)k * 128 + 2 * L);
        float wlo = bflo(wp), whi = bfhi(wp);
        unsigned x0 = *reinterpret_cast<const unsigned*>(xrow + (size_t)k * 128 + be);
        float xa = bflo(x0), xb = bfhi(x0);
        if (g == 0) {
            a0 += wlo * xa * ea.x;
            a1 += whi * xb * ea.x;
        } else if (g == 1) {
            float b0 = wlo * xa, b1 = whi * xb;
            a0 += b0 * ea.y; a1 += b0 * ea.z; a2 += b0 * ea.w;
            a3 += b1 * ea.y; a4 += b1 * ea.z; a5 += b1 * ea.w;
        } else {
            unsigned x1 = *reinterpret_cast<const unsigned*>(xrow + (size_t)k * 128 + be + 2);
            unsigned x2 = *reinterpret_cast<const unsigned*>(xrow + (size_t)k * 128 + be + 4);
            float xc = bflo(x1), xd = bfhi(x1), xe = bflo(x2), xf = bfhi(x2);
            if (g == 2) {
                float b0 = wlo * ea.x, b1 = whi * ea.x;
                a0 += b0 * xa; a1 += b0 * xb; a2 += b0 * xc;
                a3 += b1 * xd; a4 += b1 * xe; a5 += b1 * xf;
            } else {
                a0 += wlo * (xa * ea.y + xb * ea.z + xc * ea.w) * inv_sqrt3;
                a1 += whi * (xd * ea.y + xe * ea.z + xf * ea.w) * inv_sqrt3;
            }
        }
    }
    {   // final flush
        float* row = mid + (size_t)dcur * 256 + fbase;
        atomicAdd(row + 0, a0); atomicAdd(row + 1, a1);
        if (six) {
            atomicAdd(row + 2, a2); atomicAdd(row + 3, a3);
            atomicAdd(row + 4, a4); atomicAdd(row + 5, a5);
        }
    }
}

// ---------------- fallback atomic edge kernel (ws too small) ----------------
__global__ __launch_bounds__(256) void edge_kernel_atomic(
    const float* __restrict__ xsv1, const int* __restrict__ esrc, const int* __restrict__ edst,
    const float* __restrict__ eattr, const float* __restrict__ escal,
    const float* __restrict__ W1s, const float* __restrict__ W2T,
    float* __restrict__ mid, int n_edges)
{
    int e = blockIdx.x * 256 + threadIdx.x;
    if (e >= n_edges) return;
    const float4 qa = *reinterpret_cast<const float4*>(escal + (size_t)e * 8);
    const float4 qb = *reinterpret_cast<const float4*>(escal + (size_t)e * 8 + 4);
    float h[64];
    #pragma unroll
    for (int t = 0; t < 64; t++) {
        float acc = qa.x * W1s[t]       + qa.y * W1s[64 + t]
                  + qa.z * W1s[128 + t] + qa.w * W1s[192 + t]
                  + qb.x * W1s[256 + t] + qb.y * W1s[320 + t]
                  + qb.z * W1s[384 + t] + qb.w * W1s[448 + t];
        h[t] = acc / (1.0f + __expf(-acc));
    }
    int src = esrc[e], dst = edst[e];
    const float4 ea = *reinterpret_cast<const float4*>(eattr + (size_t)e * 4);
    const float ys = ea.x, yv0 = ea.y, yv1 = ea.z, yv2 = ea.w;
    const float* __restrict__ nb = xsv1 + (size_t)src * 128;
    float* __restrict__ op = mid + (size_t)dst * 256;
    const float inv_sqrt3 = 0.5773502691896258f;
    for (int u = 0; u < 32; u++) {
        float w0 = 0.f, w1 = 0.f, w2 = 0.f, w3 = 0.f;
        const float* __restrict__ r0 = W2T + (size_t)u * 64;
        const float* __restrict__ r1 = W2T + (size_t)(32 + u) * 64;
        const float* __restrict__ r2 = W2T + (size_t)(64 + u) * 64;
        const float* __restrict__ r3 = W2T + (size_t)(96 + u) * 64;
        #pragma unroll
        for (int t = 0; t < 64; t++) {
            float hv = h[t];
            w0 += hv * r0[t]; w1 += hv * r1[t]; w2 += hv * r2[t]; w3 += hv * r3[t];
        }
        float es  = nb[u];
        float ev0 = nb[32 + 3 * u], ev1 = nb[33 + 3 * u], ev2 = nb[34 + 3 * u];
        atomicAdd(op + u,      w0 * es * ys);
        atomicAdd(op + 32 + u, w3 * (ev0 * yv0 + ev1 * yv1 + ev2 * yv2) * inv_sqrt3);
        float a1 = w1 * es;
        atomicAdd(op + 64 + 3 * u, a1 * yv0);
        atomicAdd(op + 65 + 3 * u, a1 * yv1);
        atomicAdd(op + 66 + 3 * u, a1 * yv2);
        float a2 = w2 * ys;
        atomicAdd(op + 160 + 3 * u, a2 * ev0);
        atomicAdd(op + 161 + 3 * u, a2 * ev1);
        atomicAdd(op + 162 + 3 * u, a2 * ev2);
    }
}

__global__ __launch_bounds__(256) void node_out_kernel(
    const float* __restrict__ mid, const float* __restrict__ attr_out,
    const float* __restrict__ w2s, const float* __restrict__ w2v,
    float* __restrict__ out, int n_nodes)
{
    __shared__ float sS0[1024], sS1[1024], sV0[1024], sV1[1024];
    for (int k = threadIdx.x; k < 1024; k += 256) {
        sS0[k] = w2s[k]; sS1[k] = w2s[1024 + k];
        sV0[k] = w2v[k]; sV1[k] = w2v[1024 + k];
    }
    __syncthreads();
    int j = threadIdx.x & 127;
    int half = threadIdx.x >> 7;
    int w = 0, i = 0;
    if (j >= 32) { int jj = j - 32; w = jj / 3; i = jj - 3 * w; }
    const float scale = 0.125f * 0.25f; // 1/sqrt(64) * 1/sqrt(16)
    for (int base = blockIdx.x * 2; base < n_nodes; base += gridDim.x * 2) {
        int n = base + half;
        if (n >= n_nodes) continue;
        const float* __restrict__ mr = mid + (size_t)n * 256;
        float acc = 0.0f;
        if (j < 32) {
            #pragma unroll
            for (int u = 0; u < 32; u++)
                acc += mr[u] * sS0[u * 32 + j] + mr[32 + u] * sS1[u * 32 + j];
        } else {
            #pragma unroll
            for (int u = 0; u < 32; u++)
                acc += mr[64 + 3 * u + i] * sV0[u * 32 + w] + mr[160 + 3 * u + i] * sV1[u * 32 + w];
        }
        out[(size_t)n * 128 + j] = acc * (attr_out[n] * scale);
    }
}

extern "C" void kernel_launch(void* const* d_in, const int* in_sizes, int n_in,
                              void* d_out, int out_size, void* d_ws, size_t ws_size,
                              hipStream_t stream)
{
    const float* node_input = (const float*)d_in[0];
    const float* attr_in    = (const float*)d_in[1];
    const float* attr_out   = (const float*)d_in[2];
    const int*   esrc       = (const int*)d_in[3];
    const int*   edst       = (const int*)d_in[4];
    const float* eattr      = (const float*)d_in[5];
    const float* escal      = (const float*)d_in[6];
    const float* w1s        = (const float*)d_in[7];
    const float* w1v        = (const float*)d_in[8];
    const float* Wfc1       = (const float*)d_in[9];
    const float* Wfc2       = (const float*)d_in[10];
    const float* w2s        = (const float*)d_in[11];
    const float* w2v        = (const float*)d_in[12];
    float* out = (float*)d_out;

    int n_nodes = in_sizes[0] / 128;
    int n_edges = in_sizes[3];
    int n_pad = ((n_edges + 255) / 256) * 256;
    int nblk = n_pad / 256;

    char* p = (char*)d_ws;
    auto alloc = [&](size_t bytes, size_t align) -> void* {
        size_t a = (size_t)p; a = (a + align - 1) & ~(align - 1);
        p = (char*)a; void* r = (void*)p; p += bytes; return r;
    };
    float* xsv1 = (float*)alloc((size_t)n_nodes * 128 * 4, 16);
    float* W1s  = (float*)alloc(512 * 4, 16);
    float* W2T  = (float*)alloc(8192 * 4, 16);
    float* mid  = (float*)alloc((size_t)(n_nodes + 1) * 256 * 4, 16);
    int* counts = (int*)alloc((size_t)n_nodes * 4, 16);
    int* offs   = (int*)alloc(((size_t)n_nodes + 1) * 4, 16);
    int* cursor = (int*)alloc((size_t)n_nodes * 4, 16);
    int* elist  = (int*)alloc((size_t)n_pad * 4, 16);
    int* esrc_s = (int*)alloc((size_t)n_pad * 4, 16);
    int* dst_s  = (int*)alloc(((size_t)n_pad + 4) * 4, 16);
    float4* eattr_s = (float4*)alloc((size_t)n_pad * 16, 16);
    unsigned short* W2Tb = (unsigned short*)alloc(8192 * 2, 64);
    unsigned short* wbuf = (unsigned short*)alloc((size_t)n_pad * 128 * 2, 64);
    size_t needed_base = (size_t)(p - (char*)d_ws);
    unsigned short* xrow = (unsigned short*)alloc((size_t)n_pad * 128 * 2, 64);
    size_t needed_full = (size_t)(p - (char*)d_ws);

    prep_kernel<<<32, 256, 0, stream>>>(Wfc1, Wfc2, W1s, W2T, W2Tb);
    node_in_kernel<<<2048, 256, 0, stream>>>(node_input, attr_in, w1s, w1v, xsv1, n_nodes);

    if (ws_size >= needed_full) {
        hipMemsetAsync(counts, 0, (size_t)n_nodes * sizeof(int), stream);
        hipMemsetAsync(mid, 0, (size_t)(n_nodes + 1) * 256 * sizeof(float), stream);
        count_kernel<<<(n_edges + 255) / 256, 256, 0, stream>>>(edst, counts, n_edges);
        scan_kernel<<<1, 1024, 0, stream>>>(counts, offs, cursor, n_nodes);
        scatter_kernel<<<(n_edges + 255) / 256, 256, 0, stream>>>(
            edst, esrc, eattr, cursor, elist, esrc_s, eattr_s, dst_s, n_edges);
        pad_init_kernel<<<1, 256, 0, stream>>>(esrc_s, eattr_s, dst_s, n_edges, n_pad, n_nodes);
        edge_mlp_v2<<<n_pad / 64, 256, 0, stream>>>(escal, elist, W1s, W2Tb, wbuf, n_edges);
        xperm_kernel<<<2048, 256, 0, stream>>>(xsv1, esrc_s, xrow, n_pad);
        gather_wave_kernel<<<nblk, 256, 0, stream>>>(wbuf, xrow, eattr_s, dst_s, mid);
        node_out_kernel<<<2048, 256, 0, stream>>>(mid, attr_out, w2s, w2v, out, n_nodes);
    } else {
        hipMemsetAsync(mid, 0, (size_t)(n_nodes + 1) * 256 * sizeof(float), stream);
        edge_kernel_atomic<<<(n_edges + 255) / 256, 256, 0, stream>>>(
            xsv1, esrc, edst, eattr, escal, W1s, W2T, mid, n_edges);
        node_out_kernel<<<2048, 256, 0, stream>>>(mid, attr_out, w2s, w2v, out, n_nodes);
    }
}

// Round 13
// 320.910 us; speedup vs baseline: 1.7798x; 1.5566x over previous
//
#include <hip/hip_runtime.h>

// Convolution_1228360646680 — equivariant graph conv, wave-per-node gather
// N=25000, E=400000, MUL=32, NSC=8, HID=64
//
// Fast path:
//   prep / node_in / CSR sort: as validated (rounds 6-12)
//   edge_mlp_v2: MFMA per 16-edge tile + LDS transpose -> wbuf[k][128] bf16 row-major
//   gather_node: WAVE per node; per edge k (uniform in wave): scalar eattr/esrc loads,
//             lane L reads w-cols {2L,2L+1} (coalesced uint) + 2-6 contiguous f32 from
//             the L3-resident xsv1 row; 2-6 register accumulators; plain stores to mid.
//             No atomics, no xperm/xrow, no dst list, no memset, no pad.
//   node_out: out[n][128] = b[n]/sqrt(64)/sqrt(16) * (mid @ w2)
// Fallback (ws too small): atomic scatter-add + node_out.

typedef __attribute__((ext_vector_type(8))) short bf16x8;
typedef __attribute__((ext_vector_type(4))) float f32x4;

__device__ __forceinline__ unsigned bf16r(float x) {
    unsigned u = __float_as_uint(x);
    return (u + 0x7fffu + ((u >> 16) & 1u)) >> 16;   // RNE
}
__device__ __forceinline__ float bflo(unsigned p) { return __uint_as_float(p << 16); }
__device__ __forceinline__ float bfhi(unsigned p) { return __uint_as_float(p & 0xffff0000u); }

__global__ __launch_bounds__(256) void prep_kernel(
    const float* __restrict__ Wfc1, const float* __restrict__ Wfc2,
    float* __restrict__ W1s, float* __restrict__ W2T, unsigned short* __restrict__ W2Tb)
{
    int t = blockIdx.x * 256 + threadIdx.x;
    const float inv_sqrt_nsc = 0.35355339059327373f; // 1/sqrt(8)
    if (t < 8 * 64) W1s[t] = Wfc1[t] * inv_sqrt_nsc;
    if (t < 64 * 128) {
        int r = t >> 7, c = t & 127;
        float v = Wfc2[t] * 0.125f;                  // 1/sqrt(64)
        W2T[c * 64 + r] = v;
        W2Tb[c * 64 + r] = (unsigned short)bf16r(v);
    }
}

__global__ __launch_bounds__(256) void node_in_kernel(
    const float* __restrict__ node_input, const float* __restrict__ attr_in,
    const float* __restrict__ w1s, const float* __restrict__ w1v,
    float* __restrict__ xsv1, int n_nodes)
{
    __shared__ float sWs[1024], sWv[1024], srow[2][128];
    for (int k = threadIdx.x; k < 1024; k += 256) { sWs[k] = w1s[k]; sWv[k] = w1v[k]; }
    int j = threadIdx.x & 127;
    int half = threadIdx.x >> 7;
    int w = 0, i = 0;
    if (j >= 32) { int jj = j - 32; w = jj / 3; i = jj - 3 * w; }
    const float inv1 = 0.17677669529663687f; // 1/sqrt(32)
    for (int base = blockIdx.x * 2; base < n_nodes; base += gridDim.x * 2) {
        int n = base + half;
        __syncthreads();
        if (n < n_nodes) srow[half][j] = node_input[(size_t)n * 128 + j];
        __syncthreads();
        if (n < n_nodes) {
            float acc = 0.0f;
            if (j < 32) {
                #pragma unroll
                for (int u = 0; u < 32; u++) acc += srow[half][u] * sWs[u * 32 + j];
            } else {
                #pragma unroll
                for (int u = 0; u < 32; u++) acc += srow[half][32 + 3 * u + i] * sWv[u * 32 + w];
            }
            xsv1[(size_t)n * 128 + j] = acc * (attr_in[n] * inv1);
        }
    }
}

// ---------------- CSR build ----------------
__global__ __launch_bounds__(256) void count_kernel(
    const int* __restrict__ edst, int* __restrict__ counts, int n_edges)
{
    int e = blockIdx.x * 256 + threadIdx.x;
    if (e < n_edges) atomicAdd(&counts[edst[e]], 1);
}

__global__ __launch_bounds__(1024) void scan_kernel(
    const int* __restrict__ counts, int* __restrict__ offs, int* __restrict__ cursor, int n)
{
    __shared__ int part[1024];
    int tid = threadIdx.x;
    int chunk = (n + 1023) / 1024;
    int begin = tid * chunk;
    int end = begin + chunk; if (end > n) end = n;
    int s = 0;
    for (int i = begin; i < end; i++) s += counts[i];
    part[tid] = s;
    __syncthreads();
    for (int off = 1; off < 1024; off <<= 1) {
        int v = (tid >= off) ? part[tid - off] : 0;
        __syncthreads();
        part[tid] += v;
        __syncthreads();
    }
    int base = (tid == 0) ? 0 : part[tid - 1];
    for (int i = begin; i < end; i++) {
        offs[i] = base; cursor[i] = base;
        base += counts[i];
    }
    if (tid == 1023) offs[n] = part[1023];
}

__global__ __launch_bounds__(256) void scatter_kernel(
    const int* __restrict__ edst, const int* __restrict__ esrc,
    const float* __restrict__ eattr,
    int* __restrict__ cursor, int* __restrict__ elist,
    int* __restrict__ esrc_s, float4* __restrict__ eattr_s, int n_edges)
{
    int e = blockIdx.x * 256 + threadIdx.x;
    if (e < n_edges) {
        int d = edst[e];
        int p = atomicAdd(&cursor[d], 1);
        elist[p] = e;
        esrc_s[p] = esrc[e];
        eattr_s[p] = *reinterpret_cast<const float4*>(eattr + (size_t)e * 4);
    }
}

// ---------------- edge MLP via MFMA -> row-major bf16 wbuf (coalesced) ----------------
__global__ __launch_bounds__(256) void edge_mlp_v2(
    const float* __restrict__ escal, const int* __restrict__ elist,
    const float* __restrict__ W1s, const unsigned short* __restrict__ W2Tb,
    unsigned short* __restrict__ wbuf, int n_edges)
{
    __shared__ unsigned short w_lds[4][2048];   // 4 waves x 16x128 bf16 (tile-frag layout)

    int tid = threadIdx.x;
    int wv = tid >> 6, l = tid & 63;
    int lm = l & 15, lk = l >> 4;
    int kbase = blockIdx.x * 64;
    int rt = blockIdx.x * 4 + wv;
    int kidx = rt * 16 + lm;
    int k0 = lk * 8;

    bf16x8 bf[8][2];
    #pragma unroll
    for (int t = 0; t < 8; t++) {
        int n = t * 16 + lm;
        bf[t][0] = *reinterpret_cast<const bf16x8*>(W2Tb + n * 64 + k0);
        bf[t][1] = *reinterpret_cast<const bf16x8*>(W2Tb + n * 64 + k0 + 32);
    }

    float q[8];
    if (kidx < n_edges) {
        int e = elist[kidx];
        float4 qa = *reinterpret_cast<const float4*>(escal + (size_t)e * 8);
        float4 qb = *reinterpret_cast<const float4*>(escal + (size_t)e * 8 + 4);
        q[0] = qa.x; q[1] = qa.y; q[2] = qa.z; q[3] = qa.w;
        q[4] = qb.x; q[5] = qb.y; q[6] = qb.z; q[7] = qb.w;
    } else {
        #pragma unroll
        for (int i = 0; i < 8; i++) q[i] = 0.f;
    }

    union Af { bf16x8 v; unsigned u[4]; };
    Af af0, af1;
    #pragma unroll
    for (int half = 0; half < 2; half++) {
        int kb = k0 + half * 32;
        float h[8];
        #pragma unroll
        for (int i = 0; i < 8; i++) h[i] = 0.f;
        #pragma unroll
        for (int in = 0; in < 8; in++) {
            float qi = q[in];
            float4 wa = *reinterpret_cast<const float4*>(W1s + in * 64 + kb);
            float4 wb = *reinterpret_cast<const float4*>(W1s + in * 64 + kb + 4);
            h[0] += qi * wa.x; h[1] += qi * wa.y; h[2] += qi * wa.z; h[3] += qi * wa.w;
            h[4] += qi * wb.x; h[5] += qi * wb.y; h[6] += qi * wb.z; h[7] += qi * wb.w;
        }
        unsigned* dst = half ? af1.u : af0.u;
        #pragma unroll
        for (int p = 0; p < 4; p++) {
            float s0 = h[2 * p], s1 = h[2 * p + 1];
            s0 = s0 / (1.0f + __expf(-s0));
            s1 = s1 / (1.0f + __expf(-s1));
            dst[p] = bf16r(s0) | (bf16r(s1) << 16);
        }
    }

    #pragma unroll
    for (int t = 0; t < 8; t++) {
        f32x4 a4 = {0.f, 0.f, 0.f, 0.f};
        a4 = __builtin_amdgcn_mfma_f32_16x16x32_bf16(af0.v, bf[t][0], a4, 0, 0, 0);
        a4 = __builtin_amdgcn_mfma_f32_16x16x32_bf16(af1.v, bf[t][1], a4, 0, 0, 0);
        unsigned s0 = bf16r(a4[0]) | (bf16r(a4[1]) << 16);
        unsigned s1 = bf16r(a4[2]) | (bf16r(a4[3]) << 16);
        *reinterpret_cast<uint2*>(&w_lds[wv][t * 256 + l * 4]) = make_uint2(s0, s1);
    }
    __syncthreads();

    #pragma unroll
    for (int s = 0; s < 4; s++) {
        int flat = s * 256 + tid;
        int m = flat >> 4;
        int part = flat & 15;
        int wv2 = m >> 4, m2 = m & 15;
        union { unsigned short us[8]; uint4 v; } pk;
        #pragma unroll
        for (int z = 0; z < 8; z++) {
            int c = part * 8 + z;
            int ct = c >> 4, nn = c & 15;
            pk.us[z] = w_lds[wv2][ct * 256 + ((m2 >> 2) << 6) + (nn << 2) + (m2 & 3)];
        }
        *reinterpret_cast<uint4*>(wbuf + (size_t)(kbase + m) * 128 + part * 8) = pk.v;
    }
}

// ---------------- gather: wave per node, no atomics, direct xsv1 (L3) ----------------
__global__ __launch_bounds__(256) void gather_node_kernel(
    const unsigned short* __restrict__ wbuf, const float* __restrict__ xsv1,
    const int* __restrict__ esrc_s, const float4* __restrict__ eattr_s,
    const int* __restrict__ offs, float* __restrict__ mid, int n_nodes)
{
    int tid = threadIdx.x;
    int wv = __builtin_amdgcn_readfirstlane(tid >> 6);   // force wave-uniform
    int L = tid & 63;
    int n = blockIdx.x * 4 + wv;
    if (n >= n_nodes) return;
    int g = L >> 4;

    int be, fbase; bool six;
    if (g == 0)      { be = 2 * L;       fbase = 2 * L;      six = false; }
    else if (g == 1) { be = 2 * L - 32;  fbase = 6 * L - 32; six = true;  }
    else if (g == 2) { be = 6 * L - 160; fbase = 6 * L - 32; six = true;  }
    else             { be = 6 * L - 256; fbase = 2 * L - 64; six = false; }

    const float inv_sqrt3 = 0.5773502691896258f;
    float a0 = 0.f, a1 = 0.f, a2 = 0.f, a3 = 0.f, a4 = 0.f, a5 = 0.f;
    int start = offs[n], end = offs[n + 1];

    #pragma unroll 4
    for (int k = start; k < end; k++) {
        float4 ea = eattr_s[k];                               // scalar (k uniform)
        unsigned wp = *reinterpret_cast<const unsigned*>(wbuf + (size_t)k * 128 + 2 * L);
        float wlo = bflo(wp), whi = bfhi(wp);
        int src = esrc_s[k];                                  // scalar
        const float* __restrict__ nb = xsv1 + (size_t)src * 128;
        if (g == 0) {
            float2 x0 = *reinterpret_cast<const float2*>(nb + be);
            a0 += wlo * x0.x * ea.x;
            a1 += whi * x0.y * ea.x;
        } else if (g == 1) {
            float2 x0 = *reinterpret_cast<const float2*>(nb + be);
            float b0 = wlo * x0.x, b1 = whi * x0.y;
            a0 += b0 * ea.y; a1 += b0 * ea.z; a2 += b0 * ea.w;
            a3 += b1 * ea.y; a4 += b1 * ea.z; a5 += b1 * ea.w;
        } else {
            float2 x0 = *reinterpret_cast<const float2*>(nb + be);
            float2 x1 = *reinterpret_cast<const float2*>(nb + be + 2);
            float2 x2 = *reinterpret_cast<const float2*>(nb + be + 4);
            if (g == 2) {
                float b0 = wlo * ea.x, b1 = whi * ea.x;
                a0 += b0 * x0.x; a1 += b0 * x0.y; a2 += b0 * x1.x;
                a3 += b1 * x1.y; a4 += b1 * x2.x; a5 += b1 * x2.y;
            } else {
                a0 += wlo * (x0.x * ea.y + x0.y * ea.z + x1.x * ea.w) * inv_sqrt3;
                a1 += whi * (x1.y * ea.y + x2.x * ea.z + x2.y * ea.w) * inv_sqrt3;
            }
        }
    }

    float* row = mid + (size_t)n * 256 + fbase;
    *reinterpret_cast<float2*>(row) = make_float2(a0, a1);
    if (six) {
        *reinterpret_cast<float2*>(row + 2) = make_float2(a2, a3);
        *reinterpret_cast<float2*>(row + 4) = make_float2(a4, a5);
    }
}

// ---------------- fallback atomic edge kernel (ws too small) ----------------
__global__ __launch_bounds__(256) void edge_kernel_atomic(
    const float* __restrict__ xsv1, const int* __restrict__ esrc, const int* __restrict__ edst,
    const float* __restrict__ eattr, const float* __restrict__ escal,
    const float* __restrict__ W1s, const float* __restrict__ W2T,
    float* __restrict__ mid, int n_edges)
{
    int e = blockIdx.x * 256 + threadIdx.x;
    if (e >= n_edges) return;
    const float4 qa = *reinterpret_cast<const float4*>(escal + (size_t)e * 8);
    const float4 qb = *reinterpret_cast<const float4*>(escal + (size_t)e * 8 + 4);
    float h[64];
    #pragma unroll
    for (int t = 0; t < 64; t++) {
        float acc = qa.x * W1s[t]       + qa.y * W1s[64 + t]
                  + qa.z * W1s[128 + t] + qa.w * W1s[192 + t]
                  + qb.x * W1s[256 + t] + qb.y * W1s[320 + t]
                  + qb.z * W1s[384 + t] + qb.w * W1s[448 + t];
        h[t] = acc / (1.0f + __expf(-acc));
    }
    int src = esrc[e], dst = edst[e];
    const float4 ea = *reinterpret_cast<const float4*>(eattr + (size_t)e * 4);
    const float ys = ea.x, yv0 = ea.y, yv1 = ea.z, yv2 = ea.w;
    const float* __restrict__ nb = xsv1 + (size_t)src * 128;
    float* __restrict__ op = mid + (size_t)dst * 256;
    const float inv_sqrt3 = 0.5773502691896258f;
    for (int u = 0; u < 32; u++) {
        float w0 = 0.f, w1 = 0.f, w2 = 0.f, w3 = 0.f;
        const float* __restrict__ r0 = W2T + (size_t)u * 64;
        const float* __restrict__ r1 = W2T + (size_t)(32 + u) * 64;
        const float* __restrict__ r2 = W2T + (size_t)(64 + u) * 64;
        const float* __restrict__ r3 = W2T + (size_t)(96 + u) * 64;
        #pragma unroll
        for (int t = 0; t < 64; t++) {
            float hv = h[t];
            w0 += hv * r0[t]; w1 += hv * r1[t]; w2 += hv * r2[t]; w3 += hv * r3[t];
        }
        float es  = nb[u];
        float ev0 = nb[32 + 3 * u], ev1 = nb[33 + 3 * u], ev2 = nb[34 + 3 * u];
        atomicAdd(op + u,      w0 * es * ys);
        atomicAdd(op + 32 + u, w3 * (ev0 * yv0 + ev1 * yv1 + ev2 * yv2) * inv_sqrt3);
        float a1 = w1 * es;
        atomicAdd(op + 64 + 3 * u, a1 * yv0);
        atomicAdd(op + 65 + 3 * u, a1 * yv1);
        atomicAdd(op + 66 + 3 * u, a1 * yv2);
        float a2 = w2 * ys;
        atomicAdd(op + 160 + 3 * u, a2 * ev0);
        atomicAdd(op + 161 + 3 * u, a2 * ev1);
        atomicAdd(op + 162 + 3 * u, a2 * ev2);
    }
}

__global__ __launch_bounds__(256) void node_out_kernel(
    const float* __restrict__ mid, const float* __restrict__ attr_out,
    const float* __restrict__ w2s, const float* __restrict__ w2v,
    float* __restrict__ out, int n_nodes)
{
    __shared__ float sS0[1024], sS1[1024], sV0[1024], sV1[1024];
    for (int k = threadIdx.x; k < 1024; k += 256) {
        sS0[k] = w2s[k]; sS1[k] = w2s[1024 + k];
        sV0[k] = w2v[k]; sV1[k] = w2v[1024 + k];
    }
    __syncthreads();
    int j = threadIdx.x & 127;
    int half = threadIdx.x >> 7;
    int w = 0, i = 0;
    if (j >= 32) { int jj = j - 32; w = jj / 3; i = jj - 3 * w; }
    const float scale = 0.125f * 0.25f; // 1/sqrt(64) * 1/sqrt(16)
    for (int base = blockIdx.x * 2; base < n_nodes; base += gridDim.x * 2) {
        int n = base + half;
        if (n >= n_nodes) continue;
        const float* __restrict__ mr = mid + (size_t)n * 256;
        float acc = 0.0f;
        if (j < 32) {
            #pragma unroll
            for (int u = 0; u < 32; u++)
                acc += mr[u] * sS0[u * 32 + j] + mr[32 + u] * sS1[u * 32 + j];
        } else {
            #pragma unroll
            for (int u = 0; u < 32; u++)
                acc += mr[64 + 3 * u + i] * sV0[u * 32 + w] + mr[160 + 3 * u + i] * sV1[u * 32 + w];
        }
        out[(size_t)n * 128 + j] = acc * (attr_out[n] * scale);
    }
}

extern "C" void kernel_launch(void* const* d_in, const int* in_sizes, int n_in,
                              void* d_out, int out_size, void* d_ws, size_t ws_size,
                              hipStream_t stream)
{
    const float* node_input = (const float*)d_in[0];
    const float* attr_in    = (const float*)d_in[1];
    const float* attr_out   = (const float*)d_in[2];
    const int*   esrc       = (const int*)d_in[3];
    const int*   edst       = (const int*)d_in[4];
    const float* eattr      = (const float*)d_in[5];
    const float* escal      = (const float*)d_in[6];
    const float* w1s        = (const float*)d_in[7];
    const float* w1v        = (const float*)d_in[8];
    const float* Wfc1       = (const float*)d_in[9];
    const float* Wfc2       = (const float*)d_in[10];
    const float* w2s        = (const float*)d_in[11];
    const float* w2v        = (const float*)d_in[12];
    float* out = (float*)d_out;

    int n_nodes = in_sizes[0] / 128;
    int n_edges = in_sizes[3];
    int n_pad = ((n_edges + 255) / 256) * 256;

    char* p = (char*)d_ws;
    auto alloc = [&](size_t bytes, size_t align) -> void* {
        size_t a = (size_t)p; a = (a + align - 1) & ~(align - 1);
        p = (char*)a; void* r = (void*)p; p += bytes; return r;
    };
    float* xsv1 = (float*)alloc((size_t)n_nodes * 128 * 4, 16);
    float* W1s  = (float*)alloc(512 * 4, 16);
    float* W2T  = (float*)alloc(8192 * 4, 16);
    float* mid  = (float*)alloc((size_t)n_nodes * 256 * 4, 16);
    int* counts = (int*)alloc((size_t)n_nodes * 4, 16);
    int* offs   = (int*)alloc(((size_t)n_nodes + 1) * 4, 16);
    int* cursor = (int*)alloc((size_t)n_nodes * 4, 16);
    int* elist  = (int*)alloc((size_t)n_pad * 4, 16);
    int* esrc_s = (int*)alloc((size_t)n_pad * 4, 16);
    float4* eattr_s = (float4*)alloc((size_t)n_pad * 16, 16);
    unsigned short* W2Tb = (unsigned short*)alloc(8192 * 2, 64);
    unsigned short* wbuf = (unsigned short*)alloc((size_t)n_pad * 128 * 2, 64);
    size_t needed = (size_t)(p - (char*)d_ws);

    prep_kernel<<<32, 256, 0, stream>>>(Wfc1, Wfc2, W1s, W2T, W2Tb);
    node_in_kernel<<<2048, 256, 0, stream>>>(node_input, attr_in, w1s, w1v, xsv1, n_nodes);

    if (ws_size >= needed) {
        hipMemsetAsync(counts, 0, (size_t)n_nodes * sizeof(int), stream);
        count_kernel<<<(n_edges + 255) / 256, 256, 0, stream>>>(edst, counts, n_edges);
        scan_kernel<<<1, 1024, 0, stream>>>(counts, offs, cursor, n_nodes);
        scatter_kernel<<<(n_edges + 255) / 256, 256, 0, stream>>>(
            edst, esrc, eattr, cursor, elist, esrc_s, eattr_s, n_edges);
        edge_mlp_v2<<<n_pad / 64, 256, 0, stream>>>(escal, elist, W1s, W2Tb, wbuf, n_edges);
        gather_node_kernel<<<(n_nodes + 3) / 4, 256, 0, stream>>>(
            wbuf, xsv1, esrc_s, eattr_s, offs, mid, n_nodes);
        node_out_kernel<<<2048, 256, 0, stream>>>(mid, attr_out, w2s, w2v, out, n_nodes);
    } else {
        hipMemsetAsync(mid, 0, (size_t)n_nodes * 256 * sizeof(float), stream);
        edge_kernel_atomic<<<(n_edges + 255) / 256, 256, 0, stream>>>(
            xsv1, esrc, edst, eattr, escal, W1s, W2T, mid, n_edges);
        node_out_kernel<<<2048, 256, 0, stream>>>(mid, attr_out, w2s, w2v, out, n_nodes);
    }
}

// Round 14
// 320.420 us; speedup vs baseline: 1.7825x; 1.0015x over previous
//
#include <hip/hip_runtime.h>

// Convolution_1228360646680 — equivariant graph conv, wave-per-node gather v2
// N=25000, E=400000, MUL=32, NSC=8, HID=64
//
// Fast path:
//   prep / node_in / CSR sort: as validated (rounds 6-13)
//   edge_mlp_v3: MFMA per 16-edge tile; C-frags stored RAW in tile layout
//             (coalesced uint2 stores, NO LDS, no barrier) — round-5/6 proven path
//   gather_node_v2: WAVE per node; per edge k (uniform): lane L pulls cols
//             {2L,2L+1} with ONE 16B uint4 from the tile layout (sel=k&3 uniform;
//             same 16B serves 4 consecutive edges via L1); x from L3-resident
//             xsv1 (f32); 2-6 register accumulators; plain stores to mid.
//   node_out: out[n][128] = b[n]/sqrt(64)/sqrt(16) * (mid @ w2)
// Fallback (ws too small): atomic scatter-add + node_out.

typedef __attribute__((ext_vector_type(8))) short bf16x8;
typedef __attribute__((ext_vector_type(4))) float f32x4;

__device__ __forceinline__ unsigned bf16r(float x) {
    unsigned u = __float_as_uint(x);
    return (u + 0x7fffu + ((u >> 16) & 1u)) >> 16;   // RNE
}
__device__ __forceinline__ float bflo(unsigned p) { return __uint_as_float(p << 16); }
__device__ __forceinline__ float bfhi(unsigned p) { return __uint_as_float(p & 0xffff0000u); }

__global__ __launch_bounds__(256) void prep_kernel(
    const float* __restrict__ Wfc1, const float* __restrict__ Wfc2,
    float* __restrict__ W1s, float* __restrict__ W2T, unsigned short* __restrict__ W2Tb)
{
    int t = blockIdx.x * 256 + threadIdx.x;
    const float inv_sqrt_nsc = 0.35355339059327373f; // 1/sqrt(8)
    if (t < 8 * 64) W1s[t] = Wfc1[t] * inv_sqrt_nsc;
    if (t < 64 * 128) {
        int r = t >> 7, c = t & 127;
        float v = Wfc2[t] * 0.125f;                  // 1/sqrt(64)
        W2T[c * 64 + r] = v;
        W2Tb[c * 64 + r] = (unsigned short)bf16r(v);
    }
}

__global__ __launch_bounds__(256) void node_in_kernel(
    const float* __restrict__ node_input, const float* __restrict__ attr_in,
    const float* __restrict__ w1s, const float* __restrict__ w1v,
    float* __restrict__ xsv1, int n_nodes)
{
    __shared__ float sWs[1024], sWv[1024], srow[2][128];
    for (int k = threadIdx.x; k < 1024; k += 256) { sWs[k] = w1s[k]; sWv[k] = w1v[k]; }
    int j = threadIdx.x & 127;
    int half = threadIdx.x >> 7;
    int w = 0, i = 0;
    if (j >= 32) { int jj = j - 32; w = jj / 3; i = jj - 3 * w; }
    const float inv1 = 0.17677669529663687f; // 1/sqrt(32)
    for (int base = blockIdx.x * 2; base < n_nodes; base += gridDim.x * 2) {
        int n = base + half;
        __syncthreads();
        if (n < n_nodes) srow[half][j] = node_input[(size_t)n * 128 + j];
        __syncthreads();
        if (n < n_nodes) {
            float acc = 0.0f;
            if (j < 32) {
                #pragma unroll
                for (int u = 0; u < 32; u++) acc += srow[half][u] * sWs[u * 32 + j];
            } else {
                #pragma unroll
                for (int u = 0; u < 32; u++) acc += srow[half][32 + 3 * u + i] * sWv[u * 32 + w];
            }
            xsv1[(size_t)n * 128 + j] = acc * (attr_in[n] * inv1);
        }
    }
}

// ---------------- CSR build ----------------
__global__ __launch_bounds__(256) void count_kernel(
    const int* __restrict__ edst, int* __restrict__ counts, int n_edges)
{
    int e = blockIdx.x * 256 + threadIdx.x;
    if (e < n_edges) atomicAdd(&counts[edst[e]], 1);
}

__global__ __launch_bounds__(1024) void scan_kernel(
    const int* __restrict__ counts, int* __restrict__ offs, int* __restrict__ cursor, int n)
{
    __shared__ int part[1024];
    int tid = threadIdx.x;
    int chunk = (n + 1023) / 1024;
    int begin = tid * chunk;
    int end = begin + chunk; if (end > n) end = n;
    int s = 0;
    for (int i = begin; i < end; i++) s += counts[i];
    part[tid] = s;
    __syncthreads();
    for (int off = 1; off < 1024; off <<= 1) {
        int v = (tid >= off) ? part[tid - off] : 0;
        __syncthreads();
        part[tid] += v;
        __syncthreads();
    }
    int base = (tid == 0) ? 0 : part[tid - 1];
    for (int i = begin; i < end; i++) {
        offs[i] = base; cursor[i] = base;
        base += counts[i];
    }
    if (tid == 1023) offs[n] = part[1023];
}

__global__ __launch_bounds__(256) void scatter_kernel(
    const int* __restrict__ edst, const int* __restrict__ esrc,
    const float* __restrict__ eattr,
    int* __restrict__ cursor, int* __restrict__ elist,
    int* __restrict__ esrc_s, float4* __restrict__ eattr_s, int n_edges)
{
    int e = blockIdx.x * 256 + threadIdx.x;
    if (e < n_edges) {
        int d = edst[e];
        int p = atomicAdd(&cursor[d], 1);
        elist[p] = e;
        esrc_s[p] = esrc[e];
        eattr_s[p] = *reinterpret_cast<const float4*>(eattr + (size_t)e * 4);
    }
}

// ---------------- edge MLP via MFMA -> raw C-frag tile layout (no LDS) ----------------
// wbuf[(rt*8+ct)*256 + l*4 + reg], l = ((m>>2)<<4)|nn, reg = m&3  (m=k&15, nn=col&15)
__global__ __launch_bounds__(256) void edge_mlp_v3(
    const float* __restrict__ escal, const int* __restrict__ elist,
    const float* __restrict__ W1s, const unsigned short* __restrict__ W2Tb,
    unsigned short* __restrict__ wbuf, int n_edges, int nrt)
{
    int tid = threadIdx.x;
    int wv = tid >> 6, l = tid & 63;
    int lm = l & 15, lk = l >> 4;
    int rt = blockIdx.x * 4 + wv;
    int kidx = rt * 16 + lm;
    int k0 = lk * 8;

    // B fragments: 8 col-tiles x 2 K-halves (validated)
    bf16x8 bf[8][2];
    #pragma unroll
    for (int t = 0; t < 8; t++) {
        int n = t * 16 + lm;
        bf[t][0] = *reinterpret_cast<const bf16x8*>(W2Tb + n * 64 + k0);
        bf[t][1] = *reinterpret_cast<const bf16x8*>(W2Tb + n * 64 + k0 + 32);
    }

    float q[8];
    if (kidx < n_edges) {
        int e = elist[kidx];
        float4 qa = *reinterpret_cast<const float4*>(escal + (size_t)e * 8);
        float4 qb = *reinterpret_cast<const float4*>(escal + (size_t)e * 8 + 4);
        q[0] = qa.x; q[1] = qa.y; q[2] = qa.z; q[3] = qa.w;
        q[4] = qb.x; q[5] = qb.y; q[6] = qb.z; q[7] = qb.w;
    } else {
        #pragma unroll
        for (int i = 0; i < 8; i++) q[i] = 0.f;
    }

    // h = silu(q @ W1s) -> two A fragments (validated layout)
    union Af { bf16x8 v; unsigned u[4]; };
    Af af0, af1;
    #pragma unroll
    for (int half = 0; half < 2; half++) {
        int kb = k0 + half * 32;
        float h[8];
        #pragma unroll
        for (int i = 0; i < 8; i++) h[i] = 0.f;
        #pragma unroll
        for (int in = 0; in < 8; in++) {
            float qi = q[in];
            float4 wa = *reinterpret_cast<const float4*>(W1s + in * 64 + kb);
            float4 wb = *reinterpret_cast<const float4*>(W1s + in * 64 + kb + 4);
            h[0] += qi * wa.x; h[1] += qi * wa.y; h[2] += qi * wa.z; h[3] += qi * wa.w;
            h[4] += qi * wb.x; h[5] += qi * wb.y; h[6] += qi * wb.z; h[7] += qi * wb.w;
        }
        unsigned* dst = half ? af1.u : af0.u;
        #pragma unroll
        for (int p = 0; p < 4; p++) {
            float s0 = h[2 * p], s1 = h[2 * p + 1];
            s0 = s0 / (1.0f + __expf(-s0));
            s1 = s1 / (1.0f + __expf(-s1));
            dst[p] = bf16r(s0) | (bf16r(s1) << 16);
        }
    }

    // MFMA -> store C fragments raw: per tile, lane stores 4 bf16 (8B) at l*4
    if (rt < nrt) {
        #pragma unroll
        for (int t = 0; t < 8; t++) {
            f32x4 a4 = {0.f, 0.f, 0.f, 0.f};
            a4 = __builtin_amdgcn_mfma_f32_16x16x32_bf16(af0.v, bf[t][0], a4, 0, 0, 0);
            a4 = __builtin_amdgcn_mfma_f32_16x16x32_bf16(af1.v, bf[t][1], a4, 0, 0, 0);
            unsigned s0 = bf16r(a4[0]) | (bf16r(a4[1]) << 16);
            unsigned s1 = bf16r(a4[2]) | (bf16r(a4[3]) << 16);
            *reinterpret_cast<uint2*>(wbuf + ((size_t)(rt * 8 + t) * 256) + l * 4) = make_uint2(s0, s1);
        }
    }
}

// ---------------- gather: wave per node, tile-layout wbuf via one uint4/lane ----------------
__global__ __launch_bounds__(256) void gather_node_kernel(
    const unsigned short* __restrict__ wbuf, const float* __restrict__ xsv1,
    const int* __restrict__ esrc_s, const float4* __restrict__ eattr_s,
    const int* __restrict__ offs, float* __restrict__ mid, int n_nodes)
{
    int tid = threadIdx.x;
    int wv = __builtin_amdgcn_readfirstlane(tid >> 6);   // force wave-uniform
    int L = tid & 63;
    int n = blockIdx.x * 4 + wv;
    if (n >= n_nodes) return;
    int g = L >> 4;

    int be, fbase; bool six;
    if (g == 0)      { be = 2 * L;       fbase = 2 * L;      six = false; }
    else if (g == 1) { be = 2 * L - 32;  fbase = 6 * L - 32; six = true;  }
    else if (g == 2) { be = 6 * L - 160; fbase = 6 * L - 32; six = true;  }
    else             { be = 6 * L - 256; fbase = 2 * L - 64; six = false; }

    // lane-constant part of the tile-layout address (ushort units), 16B-aligned
    const int colpart = ((2 * L) >> 4) * 256 + (((2 * L) & 15) << 2);

    const float inv_sqrt3 = 0.5773502691896258f;
    float a0 = 0.f, a1 = 0.f, a2 = 0.f, a3 = 0.f, a4 = 0.f, a5 = 0.f;
    int start = offs[n], end = offs[n + 1];

    #pragma unroll 4
    for (int k = start; k < end; k++) {
        float4 ea = eattr_s[k];                               // scalar (k uniform)
        // wbuf tile-layout read: one 16B load covers cols {2L,2L+1} for 4 edges
        int epart = (k >> 4) * 2048 + (((k >> 2) & 3) << 6);  // uniform
        int sel = k & 3;                                      // uniform
        uint4 wq = *reinterpret_cast<const uint4*>(wbuf + (size_t)epart + colpart);
        unsigned ulo = (sel & 2) ? wq.y : wq.x;
        unsigned uhi = (sel & 2) ? wq.w : wq.z;
        float wlo = (sel & 1) ? bfhi(ulo) : bflo(ulo);
        float whi = (sel & 1) ? bfhi(uhi) : bflo(uhi);
        int src = esrc_s[k];                                  // scalar
        const float* __restrict__ nb = xsv1 + (size_t)src * 128;
        if (g == 0) {
            float2 x0 = *reinterpret_cast<const float2*>(nb + be);
            a0 += wlo * x0.x * ea.x;
            a1 += whi * x0.y * ea.x;
        } else if (g == 1) {
            float2 x0 = *reinterpret_cast<const float2*>(nb + be);
            float b0 = wlo * x0.x, b1 = whi * x0.y;
            a0 += b0 * ea.y; a1 += b0 * ea.z; a2 += b0 * ea.w;
            a3 += b1 * ea.y; a4 += b1 * ea.z; a5 += b1 * ea.w;
        } else {
            float2 x0 = *reinterpret_cast<const float2*>(nb + be);
            float2 x1 = *reinterpret_cast<const float2*>(nb + be + 2);
            float2 x2 = *reinterpret_cast<const float2*>(nb + be + 4);
            if (g == 2) {
                float b0 = wlo * ea.x, b1 = whi * ea.x;
                a0 += b0 * x0.x; a1 += b0 * x0.y; a2 += b0 * x1.x;
                a3 += b1 * x1.y; a4 += b1 * x2.x; a5 += b1 * x2.y;
            } else {
                a0 += wlo * (x0.x * ea.y + x0.y * ea.z + x1.x * ea.w) * inv_sqrt3;
                a1 += whi * (x1.y * ea.y + x2.x * ea.z + x2.y * ea.w) * inv_sqrt3;
            }
        }
    }

    float* row = mid + (size_t)n * 256 + fbase;
    *reinterpret_cast<float2*>(row) = make_float2(a0, a1);
    if (six) {
        *reinterpret_cast<float2*>(row + 2) = make_float2(a2, a3);
        *reinterpret_cast<float2*>(row + 4) = make_float2(a4, a5);
    }
}

// ---------------- fallback atomic edge kernel (ws too small) ----------------
__global__ __launch_bounds__(256) void edge_kernel_atomic(
    const float* __restrict__ xsv1, const int* __restrict__ esrc, const int* __restrict__ edst,
    const float* __restrict__ eattr, const float* __restrict__ escal,
    const float* __restrict__ W1s, const float* __restrict__ W2T,
    float* __restrict__ mid, int n_edges)
{
    int e = blockIdx.x * 256 + threadIdx.x;
    if (e >= n_edges) return;
    const float4 qa = *reinterpret_cast<const float4*>(escal + (size_t)e * 8);
    const float4 qb = *reinterpret_cast<const float4*>(escal + (size_t)e * 8 + 4);
    float h[64];
    #pragma unroll
    for (int t = 0; t < 64; t++) {
        float acc = qa.x * W1s[t]       + qa.y * W1s[64 + t]
                  + qa.z * W1s[128 + t] + qa.w * W1s[192 + t]
                  + qb.x * W1s[256 + t] + qb.y * W1s[320 + t]
                  + qb.z * W1s[384 + t] + qb.w * W1s[448 + t];
        h[t] = acc / (1.0f + __expf(-acc));
    }
    int src = esrc[e], dst = edst[e];
    const float4 ea = *reinterpret_cast<const float4*>(eattr + (size_t)e * 4);
    const float ys = ea.x, yv0 = ea.y, yv1 = ea.z, yv2 = ea.w;
    const float* __restrict__ nb = xsv1 + (size_t)src * 128;
    float* __restrict__ op = mid + (size_t)dst * 256;
    const float inv_sqrt3 = 0.5773502691896258f;
    for (int u = 0; u < 32; u++) {
        float w0 = 0.f, w1 = 0.f, w2 = 0.f, w3 = 0.f;
        const float* __restrict__ r0 = W2T + (size_t)u * 64;
        const float* __restrict__ r1 = W2T + (size_t)(32 + u) * 64;
        const float* __restrict__ r2 = W2T + (size_t)(64 + u) * 64;
        const float* __restrict__ r3 = W2T + (size_t)(96 + u) * 64;
        #pragma unroll
        for (int t = 0; t < 64; t++) {
            float hv = h[t];
            w0 += hv * r0[t]; w1 += hv * r1[t]; w2 += hv * r2[t]; w3 += hv * r3[t];
        }
        float es  = nb[u];
        float ev0 = nb[32 + 3 * u], ev1 = nb[33 + 3 * u], ev2 = nb[34 + 3 * u];
        atomicAdd(op + u,      w0 * es * ys);
        atomicAdd(op + 32 + u, w3 * (ev0 * yv0 + ev1 * yv1 + ev2 * yv2) * inv_sqrt3);
        float a1 = w1 * es;
        atomicAdd(op + 64 + 3 * u, a1 * yv0);
        atomicAdd(op + 65 + 3 * u, a1 * yv1);
        atomicAdd(op + 66 + 3 * u, a1 * yv2);
        float a2 = w2 * ys;
        atomicAdd(op + 160 + 3 * u, a2 * ev0);
        atomicAdd(op + 161 + 3 * u, a2 * ev1);
        atomicAdd(op + 162 + 3 * u, a2 * ev2);
    }
}

__global__ __launch_bounds__(256) void node_out_kernel(
    const float* __restrict__ mid, const float* __restrict__ attr_out,
    const float* __restrict__ w2s, const float* __restrict__ w2v,
    float* __restrict__ out, int n_nodes)
{
    __shared__ float sS0[1024], sS1[1024], sV0[1024], sV1[1024];
    for (int k = threadIdx.x; k < 1024; k += 256) {
        sS0[k] = w2s[k]; sS1[k] = w2s[1024 + k];
        sV0[k] = w2v[k]; sV1[k] = w2v[1024 + k];
    }
    __syncthreads();
    int j = threadIdx.x & 127;
    int half = threadIdx.x >> 7;
    int w = 0, i = 0;
    if (j >= 32) { int jj = j - 32; w = jj / 3; i = jj - 3 * w; }
    const float scale = 0.125f * 0.25f; // 1/sqrt(64) * 1/sqrt(16)
    for (int base = blockIdx.x * 2; base < n_nodes; base += gridDim.x * 2) {
        int n = base + half;
        if (n >= n_nodes) continue;
        const float* __restrict__ mr = mid + (size_t)n * 256;
        float acc = 0.0f;
        if (j < 32) {
            #pragma unroll
            for (int u = 0; u < 32; u++)
                acc += mr[u] * sS0[u * 32 + j] + mr[32 + u] * sS1[u * 32 + j];
        } else {
            #pragma unroll
            for (int u = 0; u < 32; u++)
                acc += mr[64 + 3 * u + i] * sV0[u * 32 + w] + mr[160 + 3 * u + i] * sV1[u * 32 + w];
        }
        out[(size_t)n * 128 + j] = acc * (attr_out[n] * scale);
    }
}

extern "C" void kernel_launch(void* const* d_in, const int* in_sizes, int n_in,
                              void* d_out, int out_size, void* d_ws, size_t ws_size,
                              hipStream_t stream)
{
    const float* node_input = (const float*)d_in[0];
    const float* attr_in    = (const float*)d_in[1];
    const float* attr_out   = (const float*)d_in[2];
    const int*   esrc       = (const int*)d_in[3];
    const int*   edst       = (const int*)d_in[4];
    const float* eattr      = (const float*)d_in[5];
    const float* escal      = (const float*)d_in[6];
    const float* w1s        = (const float*)d_in[7];
    const float* w1v        = (const float*)d_in[8];
    const float* Wfc1       = (const float*)d_in[9];
    const float* Wfc2       = (const float*)d_in[10];
    const float* w2s        = (const float*)d_in[11];
    const float* w2v        = (const float*)d_in[12];
    float* out = (float*)d_out;

    int n_nodes = in_sizes[0] / 128;
    int n_edges = in_sizes[3];
    int nrt = (n_edges + 15) / 16;           // 16-edge row tiles
    int nrt4 = (nrt + 3) / 4;                // edge_mlp blocks

    char* p = (char*)d_ws;
    auto alloc = [&](size_t bytes, size_t align) -> void* {
        size_t a = (size_t)p; a = (a + align - 1) & ~(align - 1);
        p = (char*)a; void* r = (void*)p; p += bytes; return r;
    };
    float* xsv1 = (float*)alloc((size_t)n_nodes * 128 * 4, 16);
    float* W1s  = (float*)alloc(512 * 4, 16);
    float* W2T  = (float*)alloc(8192 * 4, 16);
    float* mid  = (float*)alloc((size_t)n_nodes * 256 * 4, 16);
    int* counts = (int*)alloc((size_t)n_nodes * 4, 16);
    int* offs   = (int*)alloc(((size_t)n_nodes + 1) * 4, 16);
    int* cursor = (int*)alloc((size_t)n_nodes * 4, 16);
    int* elist  = (int*)alloc((size_t)nrt * 16 * 4, 16);
    int* esrc_s = (int*)alloc((size_t)n_edges * 4, 16);
    float4* eattr_s = (float4*)alloc((size_t)n_edges * 16, 16);
    unsigned short* W2Tb = (unsigned short*)alloc(8192 * 2, 64);
    unsigned short* wbuf = (unsigned short*)alloc((size_t)nrt * 8 * 256 * 2, 64);
    size_t needed = (size_t)(p - (char*)d_ws);

    prep_kernel<<<32, 256, 0, stream>>>(Wfc1, Wfc2, W1s, W2T, W2Tb);
    node_in_kernel<<<2048, 256, 0, stream>>>(node_input, attr_in, w1s, w1v, xsv1, n_nodes);

    if (ws_size >= needed) {
        hipMemsetAsync(counts, 0, (size_t)n_nodes * sizeof(int), stream);
        count_kernel<<<(n_edges + 255) / 256, 256, 0, stream>>>(edst, counts, n_edges);
        scan_kernel<<<1, 1024, 0, stream>>>(counts, offs, cursor, n_nodes);
        scatter_kernel<<<(n_edges + 255) / 256, 256, 0, stream>>>(
            edst, esrc, eattr, cursor, elist, esrc_s, eattr_s, n_edges);
        edge_mlp_v3<<<nrt4, 256, 0, stream>>>(escal, elist, W1s, W2Tb, wbuf, n_edges, nrt);
        gather_node_kernel<<<(n_nodes + 3) / 4, 256, 0, stream>>>(
            wbuf, xsv1, esrc_s, eattr_s, offs, mid, n_nodes);
        node_out_kernel<<<2048, 256, 0, stream>>>(mid, attr_out, w2s, w2v, out, n_nodes);
    } else {
        hipMemsetAsync(mid, 0, (size_t)n_nodes * 256 * sizeof(float), stream);
        edge_kernel_atomic<<<(n_edges + 255) / 256, 256, 0, stream>>>(
            xsv1, esrc, edst, eattr, escal, W1s, W2T, mid, n_edges);
        node_out_kernel<<<2048, 256, 0, stream>>>(mid, attr_out, w2s, w2v, out, n_nodes);
    }
}

// Round 15
// 289.037 us; speedup vs baseline: 1.9760x; 1.1086x over previous
//
#include <hip/hip_runtime.h>

// Convolution_1228360646680 — equivariant graph conv
// N=25000, E=400000, MUL=32, NSC=8, HID=64
//
// Fast path:
//   prep / node_in / CSR sort: validated (rounds 6-14); scatter also permutes
//             escal into sorted order (escal_s) — edge_mlp reads become streams
//   edge_mlp_v4: wave processes 8 consecutive 16-edge tiles; B-frags loaded ONCE
//             per wave (16KB amortized 8x); escal_s contiguous; C-frags stored RAW
//             in tile layout (coalesced uint2, no LDS, no barriers)
//   gather_node: WAVE per node; lane L pulls cols {2L,2L+1} via one uint4 from
//             tile layout; x from L3-resident xsv1 (f32); plain stores to mid
//   node_out: out[n][128] = b[n]/sqrt(64)/sqrt(16) * (mid @ w2)
// Fallback (ws too small): atomic scatter-add + node_out.

typedef __attribute__((ext_vector_type(8))) short bf16x8;
typedef __attribute__((ext_vector_type(4))) float f32x4;

__device__ __forceinline__ unsigned bf16r(float x) {
    unsigned u = __float_as_uint(x);
    return (u + 0x7fffu + ((u >> 16) & 1u)) >> 16;   // RNE
}
__device__ __forceinline__ float bflo(unsigned p) { return __uint_as_float(p << 16); }
__device__ __forceinline__ float bfhi(unsigned p) { return __uint_as_float(p & 0xffff0000u); }

__global__ __launch_bounds__(256) void prep_kernel(
    const float* __restrict__ Wfc1, const float* __restrict__ Wfc2,
    float* __restrict__ W1s, float* __restrict__ W2T, unsigned short* __restrict__ W2Tb)
{
    int t = blockIdx.x * 256 + threadIdx.x;
    const float inv_sqrt_nsc = 0.35355339059327373f; // 1/sqrt(8)
    if (t < 8 * 64) W1s[t] = Wfc1[t] * inv_sqrt_nsc;
    if (t < 64 * 128) {
        int r = t >> 7, c = t & 127;
        float v = Wfc2[t] * 0.125f;                  // 1/sqrt(64)
        W2T[c * 64 + r] = v;
        W2Tb[c * 64 + r] = (unsigned short)bf16r(v);
    }
}

__global__ __launch_bounds__(256) void node_in_kernel(
    const float* __restrict__ node_input, const float* __restrict__ attr_in,
    const float* __restrict__ w1s, const float* __restrict__ w1v,
    float* __restrict__ xsv1, int n_nodes)
{
    __shared__ float sWs[1024], sWv[1024], srow[2][128];
    for (int k = threadIdx.x; k < 1024; k += 256) { sWs[k] = w1s[k]; sWv[k] = w1v[k]; }
    int j = threadIdx.x & 127;
    int half = threadIdx.x >> 7;
    int w = 0, i = 0;
    if (j >= 32) { int jj = j - 32; w = jj / 3; i = jj - 3 * w; }
    const float inv1 = 0.17677669529663687f; // 1/sqrt(32)
    for (int base = blockIdx.x * 2; base < n_nodes; base += gridDim.x * 2) {
        int n = base + half;
        __syncthreads();
        if (n < n_nodes) srow[half][j] = node_input[(size_t)n * 128 + j];
        __syncthreads();
        if (n < n_nodes) {
            float acc = 0.0f;
            if (j < 32) {
                #pragma unroll
                for (int u = 0; u < 32; u++) acc += srow[half][u] * sWs[u * 32 + j];
            } else {
                #pragma unroll
                for (int u = 0; u < 32; u++) acc += srow[half][32 + 3 * u + i] * sWv[u * 32 + w];
            }
            xsv1[(size_t)n * 128 + j] = acc * (attr_in[n] * inv1);
        }
    }
}

// ---------------- CSR build ----------------
__global__ __launch_bounds__(256) void count_kernel(
    const int* __restrict__ edst, int* __restrict__ counts, int n_edges)
{
    int e = blockIdx.x * 256 + threadIdx.x;
    if (e < n_edges) atomicAdd(&counts[edst[e]], 1);
}

__global__ __launch_bounds__(1024) void scan_kernel(
    const int* __restrict__ counts, int* __restrict__ offs, int* __restrict__ cursor, int n)
{
    __shared__ int part[1024];
    int tid = threadIdx.x;
    int chunk = (n + 1023) / 1024;
    int begin = tid * chunk;
    int end = begin + chunk; if (end > n) end = n;
    int s = 0;
    for (int i = begin; i < end; i++) s += counts[i];
    part[tid] = s;
    __syncthreads();
    for (int off = 1; off < 1024; off <<= 1) {
        int v = (tid >= off) ? part[tid - off] : 0;
        __syncthreads();
        part[tid] += v;
        __syncthreads();
    }
    int base = (tid == 0) ? 0 : part[tid - 1];
    for (int i = begin; i < end; i++) {
        offs[i] = base; cursor[i] = base;
        base += counts[i];
    }
    if (tid == 1023) offs[n] = part[1023];
}

__global__ __launch_bounds__(256) void scatter_kernel(
    const int* __restrict__ edst, const int* __restrict__ esrc,
    const float* __restrict__ eattr, const float* __restrict__ escal,
    int* __restrict__ cursor,
    int* __restrict__ esrc_s, float4* __restrict__ eattr_s, float4* __restrict__ escal_s,
    int n_edges)
{
    int e = blockIdx.x * 256 + threadIdx.x;
    if (e < n_edges) {
        int d = edst[e];
        int p = atomicAdd(&cursor[d], 1);
        esrc_s[p] = esrc[e];
        eattr_s[p] = *reinterpret_cast<const float4*>(eattr + (size_t)e * 4);
        escal_s[2 * (size_t)p]     = *reinterpret_cast<const float4*>(escal + (size_t)e * 8);
        escal_s[2 * (size_t)p + 1] = *reinterpret_cast<const float4*>(escal + (size_t)e * 8 + 4);
    }
}

// ---------------- edge MLP via MFMA, 8 tiles/wave -> raw C-frag tile layout ----------------
// wbuf[(rt*8+ct)*256 + l*4 + reg], l = ((m>>2)<<4)|nn, reg = m&3  (m=k&15, nn=col&15)
#define TPW 8
__global__ __launch_bounds__(256) void edge_mlp_v4(
    const float4* __restrict__ escal_s,
    const float* __restrict__ W1s, const unsigned short* __restrict__ W2Tb,
    unsigned short* __restrict__ wbuf, int n_edges, int nrt)
{
    int tid = threadIdx.x;
    int wv = tid >> 6, l = tid & 63;
    int lm = l & 15, lk = l >> 4;
    int k0 = lk * 8;
    int rt0 = (blockIdx.x * 4 + wv) * TPW;

    // B fragments: loaded ONCE per wave (validated layout)
    bf16x8 bf[8][2];
    #pragma unroll
    for (int t = 0; t < 8; t++) {
        int n = t * 16 + lm;
        bf[t][0] = *reinterpret_cast<const bf16x8*>(W2Tb + n * 64 + k0);
        bf[t][1] = *reinterpret_cast<const bf16x8*>(W2Tb + n * 64 + k0 + 32);
    }

    #pragma unroll 2
    for (int t8 = 0; t8 < TPW; t8++) {
        int rt = rt0 + t8;
        if (rt >= nrt) break;
        int kidx = rt * 16 + lm;

        float q[8];
        if (kidx < n_edges) {
            float4 qa = escal_s[2 * (size_t)kidx];
            float4 qb = escal_s[2 * (size_t)kidx + 1];
            q[0] = qa.x; q[1] = qa.y; q[2] = qa.z; q[3] = qa.w;
            q[4] = qb.x; q[5] = qb.y; q[6] = qb.z; q[7] = qb.w;
        } else {
            #pragma unroll
            for (int i = 0; i < 8; i++) q[i] = 0.f;
        }

        // h = silu(q @ W1s) -> two A fragments (validated layout)
        union Af { bf16x8 v; unsigned u[4]; };
        Af af0, af1;
        #pragma unroll
        for (int half = 0; half < 2; half++) {
            int kb = k0 + half * 32;
            float h[8];
            #pragma unroll
            for (int i = 0; i < 8; i++) h[i] = 0.f;
            #pragma unroll
            for (int in = 0; in < 8; in++) {
                float qi = q[in];
                float4 wa = *reinterpret_cast<const float4*>(W1s + in * 64 + kb);
                float4 wb = *reinterpret_cast<const float4*>(W1s + in * 64 + kb + 4);
                h[0] += qi * wa.x; h[1] += qi * wa.y; h[2] += qi * wa.z; h[3] += qi * wa.w;
                h[4] += qi * wb.x; h[5] += qi * wb.y; h[6] += qi * wb.z; h[7] += qi * wb.w;
            }
            unsigned* dst = half ? af1.u : af0.u;
            #pragma unroll
            for (int p = 0; p < 4; p++) {
                float s0 = h[2 * p], s1 = h[2 * p + 1];
                s0 = s0 / (1.0f + __expf(-s0));
                s1 = s1 / (1.0f + __expf(-s1));
                dst[p] = bf16r(s0) | (bf16r(s1) << 16);
            }
        }

        // MFMA -> store C fragments raw (coalesced uint2 per tile)
        #pragma unroll
        for (int t = 0; t < 8; t++) {
            f32x4 a4 = {0.f, 0.f, 0.f, 0.f};
            a4 = __builtin_amdgcn_mfma_f32_16x16x32_bf16(af0.v, bf[t][0], a4, 0, 0, 0);
            a4 = __builtin_amdgcn_mfma_f32_16x16x32_bf16(af1.v, bf[t][1], a4, 0, 0, 0);
            unsigned s0 = bf16r(a4[0]) | (bf16r(a4[1]) << 16);
            unsigned s1 = bf16r(a4[2]) | (bf16r(a4[3]) << 16);
            *reinterpret_cast<uint2*>(wbuf + ((size_t)(rt * 8 + t) * 256) + l * 4) = make_uint2(s0, s1);
        }
    }
}

// ---------------- gather: wave per node, tile-layout wbuf via one uint4/lane ----------------
__global__ __launch_bounds__(256) void gather_node_kernel(
    const unsigned short* __restrict__ wbuf, const float* __restrict__ xsv1,
    const int* __restrict__ esrc_s, const float4* __restrict__ eattr_s,
    const int* __restrict__ offs, float* __restrict__ mid, int n_nodes)
{
    int tid = threadIdx.x;
    int wv = __builtin_amdgcn_readfirstlane(tid >> 6);   // force wave-uniform
    int L = tid & 63;
    int n = blockIdx.x * 4 + wv;
    if (n >= n_nodes) return;
    int g = L >> 4;

    int be, fbase; bool six;
    if (g == 0)      { be = 2 * L;       fbase = 2 * L;      six = false; }
    else if (g == 1) { be = 2 * L - 32;  fbase = 6 * L - 32; six = true;  }
    else if (g == 2) { be = 6 * L - 160; fbase = 6 * L - 32; six = true;  }
    else             { be = 6 * L - 256; fbase = 2 * L - 64; six = false; }

    const int colpart = ((2 * L) >> 4) * 256 + (((2 * L) & 15) << 2);

    const float inv_sqrt3 = 0.5773502691896258f;
    float a0 = 0.f, a1 = 0.f, a2 = 0.f, a3 = 0.f, a4 = 0.f, a5 = 0.f;
    int start = offs[n], end = offs[n + 1];

    #pragma unroll 4
    for (int k = start; k < end; k++) {
        float4 ea = eattr_s[k];                               // scalar (k uniform)
        int epart = (k >> 4) * 2048 + (((k >> 2) & 3) << 6);  // uniform
        int sel = k & 3;                                      // uniform
        uint4 wq = *reinterpret_cast<const uint4*>(wbuf + (size_t)epart + colpart);
        unsigned ulo = (sel & 2) ? wq.y : wq.x;
        unsigned uhi = (sel & 2) ? wq.w : wq.z;
        float wlo = (sel & 1) ? bfhi(ulo) : bflo(ulo);
        float whi = (sel & 1) ? bfhi(uhi) : bflo(uhi);
        int src = esrc_s[k];                                  // scalar
        const float* __restrict__ nb = xsv1 + (size_t)src * 128;
        if (g == 0) {
            float2 x0 = *reinterpret_cast<const float2*>(nb + be);
            a0 += wlo * x0.x * ea.x;
            a1 += whi * x0.y * ea.x;
        } else if (g == 1) {
            float2 x0 = *reinterpret_cast<const float2*>(nb + be);
            float b0 = wlo * x0.x, b1 = whi * x0.y;
            a0 += b0 * ea.y; a1 += b0 * ea.z; a2 += b0 * ea.w;
            a3 += b1 * ea.y; a4 += b1 * ea.z; a5 += b1 * ea.w;
        } else {
            float2 x0 = *reinterpret_cast<const float2*>(nb + be);
            float2 x1 = *reinterpret_cast<const float2*>(nb + be + 2);
            float2 x2 = *reinterpret_cast<const float2*>(nb + be + 4);
            if (g == 2) {
                float b0 = wlo * ea.x, b1 = whi * ea.x;
                a0 += b0 * x0.x; a1 += b0 * x0.y; a2 += b0 * x1.x;
                a3 += b1 * x1.y; a4 += b1 * x2.x; a5 += b1 * x2.y;
            } else {
                a0 += wlo * (x0.x * ea.y + x0.y * ea.z + x1.x * ea.w) * inv_sqrt3;
                a1 += whi * (x1.y * ea.y + x2.x * ea.z + x2.y * ea.w) * inv_sqrt3;
            }
        }
    }

    float* row = mid + (size_t)n * 256 + fbase;
    *reinterpret_cast<float2*>(row) = make_float2(a0, a1);
    if (six) {
        *reinterpret_cast<float2*>(row + 2) = make_float2(a2, a3);
        *reinterpret_cast<float2*>(row + 4) = make_float2(a4, a5);
    }
}

// ---------------- fallback atomic edge kernel (ws too small) ----------------
__global__ __launch_bounds__(256) void edge_kernel_atomic(
    const float* __restrict__ xsv1, const int* __restrict__ esrc, const int* __restrict__ edst,
    const float* __restrict__ eattr, const float* __restrict__ escal,
    const float* __restrict__ W1s, const float* __restrict__ W2T,
    float* __restrict__ mid, int n_edges)
{
    int e = blockIdx.x * 256 + threadIdx.x;
    if (e >= n_edges) return;
    const float4 qa = *reinterpret_cast<const float4*>(escal + (size_t)e * 8);
    const float4 qb = *reinterpret_cast<const float4*>(escal + (size_t)e * 8 + 4);
    float h[64];
    #pragma unroll
    for (int t = 0; t < 64; t++) {
        float acc = qa.x * W1s[t]       + qa.y * W1s[64 + t]
                  + qa.z * W1s[128 + t] + qa.w * W1s[192 + t]
                  + qb.x * W1s[256 + t] + qb.y * W1s[320 + t]
                  + qb.z * W1s[384 + t] + qb.w * W1s[448 + t];
        h[t] = acc / (1.0f + __expf(-acc));
    }
    int src = esrc[e], dst = edst[e];
    const float4 ea = *reinterpret_cast<const float4*>(eattr + (size_t)e * 4);
    const float ys = ea.x, yv0 = ea.y, yv1 = ea.z, yv2 = ea.w;
    const float* __restrict__ nb = xsv1 + (size_t)src * 128;
    float* __restrict__ op = mid + (size_t)dst * 256;
    const float inv_sqrt3 = 0.5773502691896258f;
    for (int u = 0; u < 32; u++) {
        float w0 = 0.f, w1 = 0.f, w2 = 0.f, w3 = 0.f;
        const float* __restrict__ r0 = W2T + (size_t)u * 64;
        const float* __restrict__ r1 = W2T + (size_t)(32 + u) * 64;
        const float* __restrict__ r2 = W2T + (size_t)(64 + u) * 64;
        const float* __restrict__ r3 = W2T + (size_t)(96 + u) * 64;
        #pragma unroll
        for (int t = 0; t < 64; t++) {
            float hv = h[t];
            w0 += hv * r0[t]; w1 += hv * r1[t]; w2 += hv * r2[t]; w3 += hv * r3[t];
        }
        float es  = nb[u];
        float ev0 = nb[32 + 3 * u], ev1 = nb[33 + 3 * u], ev2 = nb[34 + 3 * u];
        atomicAdd(op + u,      w0 * es * ys);
        atomicAdd(op + 32 + u, w3 * (ev0 * yv0 + ev1 * yv1 + ev2 * yv2) * inv_sqrt3);
        float a1 = w1 * es;
        atomicAdd(op + 64 + 3 * u, a1 * yv0);
        atomicAdd(op + 65 + 3 * u, a1 * yv1);
        atomicAdd(op + 66 + 3 * u, a1 * yv2);
        float a2 = w2 * ys;
        atomicAdd(op + 160 + 3 * u, a2 * ev0);
        atomicAdd(op + 161 + 3 * u, a2 * ev1);
        atomicAdd(op + 162 + 3 * u, a2 * ev2);
    }
}

__global__ __launch_bounds__(256) void node_out_kernel(
    const float* __restrict__ mid, const float* __restrict__ attr_out,
    const float* __restrict__ w2s, const float* __restrict__ w2v,
    float* __restrict__ out, int n_nodes)
{
    __shared__ float sS0[1024], sS1[1024], sV0[1024], sV1[1024];
    for (int k = threadIdx.x; k < 1024; k += 256) {
        sS0[k] = w2s[k]; sS1[k] = w2s[1024 + k];
        sV0[k] = w2v[k]; sV1[k] = w2v[1024 + k];
    }
    __syncthreads();
    int j = threadIdx.x & 127;
    int half = threadIdx.x >> 7;
    int w = 0, i = 0;
    if (j >= 32) { int jj = j - 32; w = jj / 3; i = jj - 3 * w; }
    const float scale = 0.125f * 0.25f; // 1/sqrt(64) * 1/sqrt(16)
    for (int base = blockIdx.x * 2; base < n_nodes; base += gridDim.x * 2) {
        int n = base + half;
        if (n >= n_nodes) continue;
        const float* __restrict__ mr = mid + (size_t)n * 256;
        float acc = 0.0f;
        if (j < 32) {
            #pragma unroll
            for (int u = 0; u < 32; u++)
                acc += mr[u] * sS0[u * 32 + j] + mr[32 + u] * sS1[u * 32 + j];
        } else {
            #pragma unroll
            for (int u = 0; u < 32; u++)
                acc += mr[64 + 3 * u + i] * sV0[u * 32 + w] + mr[160 + 3 * u + i] * sV1[u * 32 + w];
        }
        out[(size_t)n * 128 + j] = acc * (attr_out[n] * scale);
    }
}

extern "C" void kernel_launch(void* const* d_in, const int* in_sizes, int n_in,
                              void* d_out, int out_size, void* d_ws, size_t ws_size,
                              hipStream_t stream)
{
    const float* node_input = (const float*)d_in[0];
    const float* attr_in    = (const float*)d_in[1];
    const float* attr_out   = (const float*)d_in[2];
    const int*   esrc       = (const int*)d_in[3];
    const int*   edst       = (const int*)d_in[4];
    const float* eattr      = (const float*)d_in[5];
    const float* escal      = (const float*)d_in[6];
    const float* w1s        = (const float*)d_in[7];
    const float* w1v        = (const float*)d_in[8];
    const float* Wfc1       = (const float*)d_in[9];
    const float* Wfc2       = (const float*)d_in[10];
    const float* w2s        = (const float*)d_in[11];
    const float* w2v        = (const float*)d_in[12];
    float* out = (float*)d_out;

    int n_nodes = in_sizes[0] / 128;
    int n_edges = in_sizes[3];
    int nrt = (n_edges + 15) / 16;                 // 16-edge row tiles
    int nwave = (nrt + TPW - 1) / TPW;             // waves needed
    int nblk = (nwave + 3) / 4;                    // edge_mlp blocks

    char* p = (char*)d_ws;
    auto alloc = [&](size_t bytes, size_t align) -> void* {
        size_t a = (size_t)p; a = (a + align - 1) & ~(align - 1);
        p = (char*)a; void* r = (void*)p; p += bytes; return r;
    };
    float* xsv1 = (float*)alloc((size_t)n_nodes * 128 * 4, 16);
    float* W1s  = (float*)alloc(512 * 4, 16);
    float* W2T  = (float*)alloc(8192 * 4, 16);
    float* mid  = (float*)alloc((size_t)n_nodes * 256 * 4, 16);
    int* counts = (int*)alloc((size_t)n_nodes * 4, 16);
    int* offs   = (int*)alloc(((size_t)n_nodes + 1) * 4, 16);
    int* cursor = (int*)alloc((size_t)n_nodes * 4, 16);
    int* esrc_s = (int*)alloc((size_t)n_edges * 4, 16);
    float4* eattr_s = (float4*)alloc((size_t)n_edges * 16, 16);
    float4* escal_s = (float4*)alloc((size_t)n_edges * 32, 16);
    unsigned short* W2Tb = (unsigned short*)alloc(8192 * 2, 64);
    unsigned short* wbuf = (unsigned short*)alloc((size_t)nrt * 8 * 256 * 2, 64);
    size_t needed = (size_t)(p - (char*)d_ws);

    prep_kernel<<<32, 256, 0, stream>>>(Wfc1, Wfc2, W1s, W2T, W2Tb);
    node_in_kernel<<<2048, 256, 0, stream>>>(node_input, attr_in, w1s, w1v, xsv1, n_nodes);

    if (ws_size >= needed) {
        hipMemsetAsync(counts, 0, (size_t)n_nodes * sizeof(int), stream);
        count_kernel<<<(n_edges + 255) / 256, 256, 0, stream>>>(edst, counts, n_edges);
        scan_kernel<<<1, 1024, 0, stream>>>(counts, offs, cursor, n_nodes);
        scatter_kernel<<<(n_edges + 255) / 256, 256, 0, stream>>>(
            edst, esrc, eattr, escal, cursor, esrc_s, eattr_s, escal_s, n_edges);
        edge_mlp_v4<<<nblk, 256, 0, stream>>>(escal_s, W1s, W2Tb, wbuf, n_edges, nrt);
        gather_node_kernel<<<(n_nodes + 3) / 4, 256, 0, stream>>>(
            wbuf, xsv1, esrc_s, eattr_s, offs, mid, n_nodes);
        node_out_kernel<<<2048, 256, 0, stream>>>(mid, attr_out, w2s, w2v, out, n_nodes);
    } else {
        hipMemsetAsync(mid, 0, (size_t)n_nodes * 256 * sizeof(float), stream);
        edge_kernel_atomic<<<(n_edges + 255) / 256, 256, 0, stream>>>(
            xsv1, esrc, edst, eattr, escal, W1s, W2T, mid, n_edges);
        node_out_kernel<<<2048, 256, 0, stream>>>(mid, attr_out, w2s, w2v, out, n_nodes);
    }
}

// Round 16
// 285.933 us; speedup vs baseline: 1.9975x; 1.0109x over previous
//
#include <hip/hip_runtime.h>

// Convolution_1228360646680 — equivariant graph conv
// N=25000, E=400000, MUL=32, NSC=8, HID=64
//
// Fast path:
//   prep / node_in: validated
//   CSR: count -> scan -> scatter (elist only, 4B scattered) -> permute
//        (scattered L3 reads, coalesced writes of esrc_s/eattr_s/escal_s)
//   edge_mlp_v4: wave = 8 consecutive 16-edge tiles; B-frags loaded once/wave;
//        C-frags stored RAW in tile layout (coalesced uint2, no LDS)
//   gather_out: WAVE per node (4/block); lane L owns w-cols {2L,2L+1} via one
//        uint4 from tile layout; x from L3-resident xsv1; accs -> LDS smid;
//        fused w2 transform (LDS-staged weights) -> out. No mid round-trip.
// Fallback (ws too small): atomic scatter-add + node_out.

typedef __attribute__((ext_vector_type(8))) short bf16x8;
typedef __attribute__((ext_vector_type(4))) float f32x4;

__device__ __forceinline__ unsigned bf16r(float x) {
    unsigned u = __float_as_uint(x);
    return (u + 0x7fffu + ((u >> 16) & 1u)) >> 16;   // RNE
}
__device__ __forceinline__ float bflo(unsigned p) { return __uint_as_float(p << 16); }
__device__ __forceinline__ float bfhi(unsigned p) { return __uint_as_float(p & 0xffff0000u); }

__global__ __launch_bounds__(256) void prep_kernel(
    const float* __restrict__ Wfc1, const float* __restrict__ Wfc2,
    float* __restrict__ W1s, float* __restrict__ W2T, unsigned short* __restrict__ W2Tb)
{
    int t = blockIdx.x * 256 + threadIdx.x;
    const float inv_sqrt_nsc = 0.35355339059327373f; // 1/sqrt(8)
    if (t < 8 * 64) W1s[t] = Wfc1[t] * inv_sqrt_nsc;
    if (t < 64 * 128) {
        int r = t >> 7, c = t & 127;
        float v = Wfc2[t] * 0.125f;                  // 1/sqrt(64)
        W2T[c * 64 + r] = v;
        W2Tb[c * 64 + r] = (unsigned short)bf16r(v);
    }
}

__global__ __launch_bounds__(256) void node_in_kernel(
    const float* __restrict__ node_input, const float* __restrict__ attr_in,
    const float* __restrict__ w1s, const float* __restrict__ w1v,
    float* __restrict__ xsv1, int n_nodes)
{
    __shared__ float sWs[1024], sWv[1024], srow[2][128];
    for (int k = threadIdx.x; k < 1024; k += 256) { sWs[k] = w1s[k]; sWv[k] = w1v[k]; }
    int j = threadIdx.x & 127;
    int half = threadIdx.x >> 7;
    int w = 0, i = 0;
    if (j >= 32) { int jj = j - 32; w = jj / 3; i = jj - 3 * w; }
    const float inv1 = 0.17677669529663687f; // 1/sqrt(32)
    for (int base = blockIdx.x * 2; base < n_nodes; base += gridDim.x * 2) {
        int n = base + half;
        __syncthreads();
        if (n < n_nodes) srow[half][j] = node_input[(size_t)n * 128 + j];
        __syncthreads();
        if (n < n_nodes) {
            float acc = 0.0f;
            if (j < 32) {
                #pragma unroll
                for (int u = 0; u < 32; u++) acc += srow[half][u] * sWs[u * 32 + j];
            } else {
                #pragma unroll
                for (int u = 0; u < 32; u++) acc += srow[half][32 + 3 * u + i] * sWv[u * 32 + w];
            }
            xsv1[(size_t)n * 128 + j] = acc * (attr_in[n] * inv1);
        }
    }
}

// ---------------- CSR build ----------------
__global__ __launch_bounds__(256) void count_kernel(
    const int* __restrict__ edst, int* __restrict__ counts, int n_edges)
{
    int e = blockIdx.x * 256 + threadIdx.x;
    if (e < n_edges) atomicAdd(&counts[edst[e]], 1);
}

__global__ __launch_bounds__(1024) void scan_kernel(
    const int* __restrict__ counts, int* __restrict__ offs, int* __restrict__ cursor, int n)
{
    __shared__ int part[1024];
    int tid = threadIdx.x;
    int chunk = (n + 1023) / 1024;
    int begin = tid * chunk;
    int end = begin + chunk; if (end > n) end = n;
    int s = 0;
    for (int i = begin; i < end; i++) s += counts[i];
    part[tid] = s;
    __syncthreads();
    for (int off = 1; off < 1024; off <<= 1) {
        int v = (tid >= off) ? part[tid - off] : 0;
        __syncthreads();
        part[tid] += v;
        __syncthreads();
    }
    int base = (tid == 0) ? 0 : part[tid - 1];
    for (int i = begin; i < end; i++) {
        offs[i] = base; cursor[i] = base;
        base += counts[i];
    }
    if (tid == 1023) offs[n] = part[1023];
}

// scatter: elist only (4B scattered writes)
__global__ __launch_bounds__(256) void scatter_kernel(
    const int* __restrict__ edst, int* __restrict__ cursor,
    int* __restrict__ elist, int n_edges)
{
    int e = blockIdx.x * 256 + threadIdx.x;
    if (e < n_edges) {
        int p = atomicAdd(&cursor[edst[e]], 1);
        elist[p] = e;
    }
}

// permute: scattered L3 reads, coalesced writes
__global__ __launch_bounds__(256) void permute_kernel(
    const int* __restrict__ elist, const int* __restrict__ esrc,
    const float* __restrict__ eattr, const float* __restrict__ escal,
    int* __restrict__ esrc_s, float4* __restrict__ eattr_s, float4* __restrict__ escal_s,
    int n_edges)
{
    int k = blockIdx.x * 256 + threadIdx.x;
    if (k < n_edges) {
        int e = elist[k];
        esrc_s[k] = esrc[e];
        eattr_s[k] = *reinterpret_cast<const float4*>(eattr + (size_t)e * 4);
        escal_s[2 * (size_t)k]     = *reinterpret_cast<const float4*>(escal + (size_t)e * 8);
        escal_s[2 * (size_t)k + 1] = *reinterpret_cast<const float4*>(escal + (size_t)e * 8 + 4);
    }
}

// ---------------- edge MLP via MFMA, 8 tiles/wave -> raw C-frag tile layout ----------------
// wbuf[(rt*8+ct)*256 + l*4 + reg], l = ((m>>2)<<4)|nn, reg = m&3  (m=k&15, nn=col&15)
#define TPW 8
__global__ __launch_bounds__(256) void edge_mlp_v4(
    const float4* __restrict__ escal_s,
    const float* __restrict__ W1s, const unsigned short* __restrict__ W2Tb,
    unsigned short* __restrict__ wbuf, int n_edges, int nrt)
{
    int tid = threadIdx.x;
    int wv = tid >> 6, l = tid & 63;
    int lm = l & 15, lk = l >> 4;
    int k0 = lk * 8;
    int rt0 = (blockIdx.x * 4 + wv) * TPW;

    bf16x8 bf[8][2];
    #pragma unroll
    for (int t = 0; t < 8; t++) {
        int n = t * 16 + lm;
        bf[t][0] = *reinterpret_cast<const bf16x8*>(W2Tb + n * 64 + k0);
        bf[t][1] = *reinterpret_cast<const bf16x8*>(W2Tb + n * 64 + k0 + 32);
    }

    #pragma unroll 2
    for (int t8 = 0; t8 < TPW; t8++) {
        int rt = rt0 + t8;
        if (rt >= nrt) break;
        int kidx = rt * 16 + lm;

        float q[8];
        if (kidx < n_edges) {
            float4 qa = escal_s[2 * (size_t)kidx];
            float4 qb = escal_s[2 * (size_t)kidx + 1];
            q[0] = qa.x; q[1] = qa.y; q[2] = qa.z; q[3] = qa.w;
            q[4] = qb.x; q[5] = qb.y; q[6] = qb.z; q[7] = qb.w;
        } else {
            #pragma unroll
            for (int i = 0; i < 8; i++) q[i] = 0.f;
        }

        union Af { bf16x8 v; unsigned u[4]; };
        Af af0, af1;
        #pragma unroll
        for (int half = 0; half < 2; half++) {
            int kb = k0 + half * 32;
            float h[8];
            #pragma unroll
            for (int i = 0; i < 8; i++) h[i] = 0.f;
            #pragma unroll
            for (int in = 0; in < 8; in++) {
                float qi = q[in];
                float4 wa = *reinterpret_cast<const float4*>(W1s + in * 64 + kb);
                float4 wb = *reinterpret_cast<const float4*>(W1s + in * 64 + kb + 4);
                h[0] += qi * wa.x; h[1] += qi * wa.y; h[2] += qi * wa.z; h[3] += qi * wa.w;
                h[4] += qi * wb.x; h[5] += qi * wb.y; h[6] += qi * wb.z; h[7] += qi * wb.w;
            }
            unsigned* dst = half ? af1.u : af0.u;
            #pragma unroll
            for (int p = 0; p < 4; p++) {
                float s0 = h[2 * p], s1 = h[2 * p + 1];
                s0 = s0 / (1.0f + __expf(-s0));
                s1 = s1 / (1.0f + __expf(-s1));
                dst[p] = bf16r(s0) | (bf16r(s1) << 16);
            }
        }

        #pragma unroll
        for (int t = 0; t < 8; t++) {
            f32x4 a4 = {0.f, 0.f, 0.f, 0.f};
            a4 = __builtin_amdgcn_mfma_f32_16x16x32_bf16(af0.v, bf[t][0], a4, 0, 0, 0);
            a4 = __builtin_amdgcn_mfma_f32_16x16x32_bf16(af1.v, bf[t][1], a4, 0, 0, 0);
            unsigned s0 = bf16r(a4[0]) | (bf16r(a4[1]) << 16);
            unsigned s1 = bf16r(a4[2]) | (bf16r(a4[3]) << 16);
            *reinterpret_cast<uint2*>(wbuf + ((size_t)(rt * 8 + t) * 256) + l * 4) = make_uint2(s0, s1);
        }
    }
}

// ---------------- gather + fused node_out: wave/node, 4 nodes/block ----------------
__global__ __launch_bounds__(256) void gather_out_kernel(
    const unsigned short* __restrict__ wbuf, const float* __restrict__ xsv1,
    const int* __restrict__ esrc_s, const float4* __restrict__ eattr_s,
    const int* __restrict__ offs, const float* __restrict__ attr_out,
    const float* __restrict__ w2s, const float* __restrict__ w2v,
    float* __restrict__ out, int n_nodes)
{
    __shared__ float sW[4096];        // w2s (2048) | w2v (2048)
    __shared__ float smid[4][256];

    int tid = threadIdx.x;
    for (int idx = tid; idx < 2048; idx += 256) { sW[idx] = w2s[idx]; sW[2048 + idx] = w2v[idx]; }

    int wv = __builtin_amdgcn_readfirstlane(tid >> 6);
    int L = tid & 63;
    int n = blockIdx.x * 4 + wv;
    int g = L >> 4;

    int be, fbase; bool six;
    if (g == 0)      { be = 2 * L;       fbase = 2 * L;      six = false; }
    else if (g == 1) { be = 2 * L - 32;  fbase = 6 * L - 32; six = true;  }
    else if (g == 2) { be = 6 * L - 160; fbase = 6 * L - 32; six = true;  }
    else             { be = 6 * L - 256; fbase = 2 * L - 64; six = false; }

    const int colpart = ((2 * L) >> 4) * 256 + (((2 * L) & 15) << 2);
    const float inv_sqrt3 = 0.5773502691896258f;
    float a0 = 0.f, a1 = 0.f, a2 = 0.f, a3 = 0.f, a4 = 0.f, a5 = 0.f;

    if (n < n_nodes) {
        int start = offs[n], end = offs[n + 1];
        #pragma unroll 4
        for (int k = start; k < end; k++) {
            float4 ea = eattr_s[k];                               // scalar (k uniform)
            int epart = (k >> 4) * 2048 + (((k >> 2) & 3) << 6);  // uniform
            int sel = k & 3;                                      // uniform
            uint4 wq = *reinterpret_cast<const uint4*>(wbuf + (size_t)epart + colpart);
            unsigned ulo = (sel & 2) ? wq.y : wq.x;
            unsigned uhi = (sel & 2) ? wq.w : wq.z;
            float wlo = (sel & 1) ? bfhi(ulo) : bflo(ulo);
            float whi = (sel & 1) ? bfhi(uhi) : bflo(uhi);
            int src = esrc_s[k];                                  // scalar
            const float* __restrict__ nb = xsv1 + (size_t)src * 128;
            if (g == 0) {
                float2 x0 = *reinterpret_cast<const float2*>(nb + be);
                a0 += wlo * x0.x * ea.x;
                a1 += whi * x0.y * ea.x;
            } else if (g == 1) {
                float2 x0 = *reinterpret_cast<const float2*>(nb + be);
                float b0 = wlo * x0.x, b1 = whi * x0.y;
                a0 += b0 * ea.y; a1 += b0 * ea.z; a2 += b0 * ea.w;
                a3 += b1 * ea.y; a4 += b1 * ea.z; a5 += b1 * ea.w;
            } else {
                float2 x0 = *reinterpret_cast<const float2*>(nb + be);
                float2 x1 = *reinterpret_cast<const float2*>(nb + be + 2);
                float2 x2 = *reinterpret_cast<const float2*>(nb + be + 4);
                if (g == 2) {
                    float b0 = wlo * ea.x, b1 = whi * ea.x;
                    a0 += b0 * x0.x; a1 += b0 * x0.y; a2 += b0 * x1.x;
                    a3 += b1 * x1.y; a4 += b1 * x2.x; a5 += b1 * x2.y;
                } else {
                    a0 += wlo * (x0.x * ea.y + x0.y * ea.z + x1.x * ea.w) * inv_sqrt3;
                    a1 += whi * (x1.y * ea.y + x2.x * ea.z + x2.y * ea.w) * inv_sqrt3;
                }
            }
        }
    }

    // accs -> LDS (bijective feature mapping, validated rounds 13-15)
    float* row = &smid[wv][fbase];
    row[0] = a0; row[1] = a1;
    if (six) { row[2] = a2; row[3] = a3; row[4] = a4; row[5] = a5; }
    __syncthreads();   // covers sW staging + smid writes

    // fused node_out tail (round-7-validated math): 2 iterations x (2 nodes x 128 outs)
    int h = tid >> 7, j = tid & 127;
    int tw = 0, ti = 0;
    if (j >= 32) { int jj = j - 32; tw = jj / 3; ti = jj - 3 * tw; }
    #pragma unroll
    for (int it = 0; it < 2; it++) {
        int ln = 2 * it + h;
        int nn = blockIdx.x * 4 + ln;
        if (nn < n_nodes) {
            const float* __restrict__ sm = smid[ln];
            float o = 0.0f;
            if (j < 32) {
                #pragma unroll
                for (int u = 0; u < 32; u++)
                    o += sm[u] * sW[u * 32 + j] + sm[32 + u] * sW[1024 + u * 32 + j];
            } else {
                #pragma unroll
                for (int u = 0; u < 32; u++)
                    o += sm[64 + 3 * u + ti] * sW[2048 + u * 32 + tw]
                       + sm[160 + 3 * u + ti] * sW[3072 + u * 32 + tw];
            }
            out[(size_t)nn * 128 + j] = o * (attr_out[nn] * 0.03125f); // 1/sqrt(64)/sqrt(16)
        }
    }
}

// ---------------- fallback atomic edge kernel (ws too small) ----------------
__global__ __launch_bounds__(256) void edge_kernel_atomic(
    const float* __restrict__ xsv1, const int* __restrict__ esrc, const int* __restrict__ edst,
    const float* __restrict__ eattr, const float* __restrict__ escal,
    const float* __restrict__ W1s, const float* __restrict__ W2T,
    float* __restrict__ mid, int n_edges)
{
    int e = blockIdx.x * 256 + threadIdx.x;
    if (e >= n_edges) return;
    const float4 qa = *reinterpret_cast<const float4*>(escal + (size_t)e * 8);
    const float4 qb = *reinterpret_cast<const float4*>(escal + (size_t)e * 8 + 4);
    float h[64];
    #pragma unroll
    for (int t = 0; t < 64; t++) {
        float acc = qa.x * W1s[t]       + qa.y * W1s[64 + t]
                  + qa.z * W1s[128 + t] + qa.w * W1s[192 + t]
                  + qb.x * W1s[256 + t] + qb.y * W1s[320 + t]
                  + qb.z * W1s[384 + t] + qb.w * W1s[448 + t];
        h[t] = acc / (1.0f + __expf(-acc));
    }
    int src = esrc[e], dst = edst[e];
    const float4 ea = *reinterpret_cast<const float4*>(eattr + (size_t)e * 4);
    const float ys = ea.x, yv0 = ea.y, yv1 = ea.z, yv2 = ea.w;
    const float* __restrict__ nb = xsv1 + (size_t)src * 128;
    float* __restrict__ op = mid + (size_t)dst * 256;
    const float inv_sqrt3 = 0.5773502691896258f;
    for (int u = 0; u < 32; u++) {
        float w0 = 0.f, w1 = 0.f, w2 = 0.f, w3 = 0.f;
        const float* __restrict__ r0 = W2T + (size_t)u * 64;
        const float* __restrict__ r1 = W2T + (size_t)(32 + u) * 64;
        const float* __restrict__ r2 = W2T + (size_t)(64 + u) * 64;
        const float* __restrict__ r3 = W2T + (size_t)(96 + u) * 64;
        #pragma unroll
        for (int t = 0; t < 64; t++) {
            float hv = h[t];
            w0 += hv * r0[t]; w1 += hv * r1[t]; w2 += hv * r2[t]; w3 += hv * r3[t];
        }
        float es  = nb[u];
        float ev0 = nb[32 + 3 * u], ev1 = nb[33 + 3 * u], ev2 = nb[34 + 3 * u];
        atomicAdd(op + u,      w0 * es * ys);
        atomicAdd(op + 32 + u, w3 * (ev0 * yv0 + ev1 * yv1 + ev2 * yv2) * inv_sqrt3);
        float a1 = w1 * es;
        atomicAdd(op + 64 + 3 * u, a1 * yv0);
        atomicAdd(op + 65 + 3 * u, a1 * yv1);
        atomicAdd(op + 66 + 3 * u, a1 * yv2);
        float a2 = w2 * ys;
        atomicAdd(op + 160 + 3 * u, a2 * ev0);
        atomicAdd(op + 161 + 3 * u, a2 * ev1);
        atomicAdd(op + 162 + 3 * u, a2 * ev2);
    }
}

__global__ __launch_bounds__(256) void node_out_kernel(
    const float* __restrict__ mid, const float* __restrict__ attr_out,
    const float* __restrict__ w2s, const float* __restrict__ w2v,
    float* __restrict__ out, int n_nodes)
{
    __shared__ float sS0[1024], sS1[1024], sV0[1024], sV1[1024];
    for (int k = threadIdx.x; k < 1024; k += 256) {
        sS0[k] = w2s[k]; sS1[k] = w2s[1024 + k];
        sV0[k] = w2v[k]; sV1[k] = w2v[1024 + k];
    }
    __syncthreads();
    int j = threadIdx.x & 127;
    int half = threadIdx.x >> 7;
    int w = 0, i = 0;
    if (j >= 32) { int jj = j - 32; w = jj / 3; i = jj - 3 * w; }
    const float scale = 0.125f * 0.25f;
    for (int base = blockIdx.x * 2; base < n_nodes; base += gridDim.x * 2) {
        int n = base + half;
        if (n >= n_nodes) continue;
        const float* __restrict__ mr = mid + (size_t)n * 256;
        float acc = 0.0f;
        if (j < 32) {
            #pragma unroll
            for (int u = 0; u < 32; u++)
                acc += mr[u] * sS0[u * 32 + j] + mr[32 + u] * sS1[u * 32 + j];
        } else {
            #pragma unroll
            for (int u = 0; u < 32; u++)
                acc += mr[64 + 3 * u + i] * sV0[u * 32 + w] + mr[160 + 3 * u + i] * sV1[u * 32 + w];
        }
        out[(size_t)n * 128 + j] = acc * (attr_out[n] * scale);
    }
}

extern "C" void kernel_launch(void* const* d_in, const int* in_sizes, int n_in,
                              void* d_out, int out_size, void* d_ws, size_t ws_size,
                              hipStream_t stream)
{
    const float* node_input = (const float*)d_in[0];
    const float* attr_in    = (const float*)d_in[1];
    const float* attr_out   = (const float*)d_in[2];
    const int*   esrc       = (const int*)d_in[3];
    const int*   edst       = (const int*)d_in[4];
    const float* eattr      = (const float*)d_in[5];
    const float* escal      = (const float*)d_in[6];
    const float* w1s        = (const float*)d_in[7];
    const float* w1v        = (const float*)d_in[8];
    const float* Wfc1       = (const float*)d_in[9];
    const float* Wfc2       = (const float*)d_in[10];
    const float* w2s        = (const float*)d_in[11];
    const float* w2v        = (const float*)d_in[12];
    float* out = (float*)d_out;

    int n_nodes = in_sizes[0] / 128;
    int n_edges = in_sizes[3];
    int nrt = (n_edges + 15) / 16;                 // 16-edge row tiles
    int nwave = (nrt + TPW - 1) / TPW;
    int nblk = (nwave + 3) / 4;

    char* p = (char*)d_ws;
    auto alloc = [&](size_t bytes, size_t align) -> void* {
        size_t a = (size_t)p; a = (a + align - 1) & ~(align - 1);
        p = (char*)a; void* r = (void*)p; p += bytes; return r;
    };
    float* xsv1 = (float*)alloc((size_t)n_nodes * 128 * 4, 16);
    float* W1s  = (float*)alloc(512 * 4, 16);
    float* W2T  = (float*)alloc(8192 * 4, 16);
    float* mid  = (float*)alloc((size_t)n_nodes * 256 * 4, 16);   // fallback only
    int* counts = (int*)alloc((size_t)n_nodes * 4, 16);
    int* offs   = (int*)alloc(((size_t)n_nodes + 1) * 4, 16);
    int* cursor = (int*)alloc((size_t)n_nodes * 4, 16);
    int* elist  = (int*)alloc((size_t)n_edges * 4, 16);
    int* esrc_s = (int*)alloc((size_t)n_edges * 4, 16);
    float4* eattr_s = (float4*)alloc((size_t)n_edges * 16, 16);
    float4* escal_s = (float4*)alloc((size_t)n_edges * 32, 16);
    unsigned short* W2Tb = (unsigned short*)alloc(8192 * 2, 64);
    unsigned short* wbuf = (unsigned short*)alloc((size_t)nrt * 8 * 256 * 2, 64);
    size_t needed = (size_t)(p - (char*)d_ws);

    prep_kernel<<<32, 256, 0, stream>>>(Wfc1, Wfc2, W1s, W2T, W2Tb);
    node_in_kernel<<<2048, 256, 0, stream>>>(node_input, attr_in, w1s, w1v, xsv1, n_nodes);

    if (ws_size >= needed) {
        hipMemsetAsync(counts, 0, (size_t)n_nodes * sizeof(int), stream);
        count_kernel<<<(n_edges + 255) / 256, 256, 0, stream>>>(edst, counts, n_edges);
        scan_kernel<<<1, 1024, 0, stream>>>(counts, offs, cursor, n_nodes);
        scatter_kernel<<<(n_edges + 255) / 256, 256, 0, stream>>>(edst, cursor, elist, n_edges);
        permute_kernel<<<(n_edges + 255) / 256, 256, 0, stream>>>(
            elist, esrc, eattr, escal, esrc_s, eattr_s, escal_s, n_edges);
        edge_mlp_v4<<<nblk, 256, 0, stream>>>(escal_s, W1s, W2Tb, wbuf, n_edges, nrt);
        gather_out_kernel<<<(n_nodes + 3) / 4, 256, 0, stream>>>(
            wbuf, xsv1, esrc_s, eattr_s, offs, attr_out, w2s, w2v, out, n_nodes);
    } else {
        hipMemsetAsync(mid, 0, (size_t)n_nodes * 256 * sizeof(float), stream);
        edge_kernel_atomic<<<(n_edges + 255) / 256, 256, 0, stream>>>(
            xsv1, esrc, edst, eattr, escal, W1s, W2T, mid, n_edges);
        node_out_kernel<<<2048, 256, 0, stream>>>(mid, attr_out, w2s, w2v, out, n_nodes);
    }
}